// Round 8
// baseline (3616.939 us; speedup 1.0000x reference)
//
#include <hip/hip_runtime.h>
#include <hip/hip_bf16.h>
#include <math.h>

// ---------------- problem constants ----------------
#define Dm    512
#define Hh    8
#define NLay  6
#define DFFm  2048
#define Bb    4
#define NTOK  2048          // B * S
#define PADID 1
#define LNEPS 1e-5f
#define S2W   262144        // 512*512 elements (one [512][512] plane)

typedef __attribute__((ext_vector_type(8))) short short8;   // 8 x bf16 (4 VGPRs)
typedef __attribute__((ext_vector_type(4))) float f32x4;
typedef unsigned short u16;

__device__ __forceinline__ u16 f2bf(float f) {
    union { float f; unsigned int i; } x; x.f = f;
    unsigned int r = x.i + 0x7fffu + ((x.i >> 16) & 1u);   // RNE
    return (u16)(r >> 16);
}

// async global->LDS, 16B per lane (dest must be linear-in-lane: base+lane*16)
typedef const __attribute__((address_space(1))) void* as1cv;
typedef __attribute__((address_space(3))) void* as3v;
__device__ __forceinline__ void gl_lds16(const u16* g, u16* l) {
    __builtin_amdgcn_global_load_lds((as1cv)g, (as3v)l, 16, 0, 0);
}

// bijective XCD-chunk swizzle (m204), M fastest within an XCD's chunk so
// consecutive wgids on one XCD share the B panel (its private L2).
__device__ __forceinline__ void swz_tile(int& mt, int& nt) {
    const int nwg  = gridDim.x * gridDim.y;
    const int orig = blockIdx.y * gridDim.x + blockIdx.x;
    const int q8 = nwg >> 3, r8 = nwg & 7;
    const int xcd = orig & 7, idx = orig >> 3;
    const int wgid = (xcd < r8 ? xcd * (q8 + 1) : r8 * (q8 + 1) + (xcd - r8) * q8) + idx;
    const int MT = gridDim.y;
    mt = wgid % MT;
    nt = wgid / MT;
}

// ---- one-launch f32->bf16 conversion of all 17 weight tensors ----
struct CvtJobs {
    const float* s[17];
    u16*         d[17];
    long         n4[17];
};
__global__ __launch_bounds__(256) void cvt_many(CvtJobs j) {
    const int job = blockIdx.y;
    const long n4 = j.n4[job];
    const float* in = j.s[job];
    u16* out = j.d[job];
    long i = (long)blockIdx.x * 256 + threadIdx.x;
    const long stride = (long)gridDim.x * 256;
    for (; i < n4; i += stride) {
        float4 v = ((const float4*)in)[i];
        ushort4 o;
        o.x = f2bf(v.x); o.y = f2bf(v.y); o.z = f2bf(v.z); o.w = f2bf(v.w);
        ((ushort4*)out)[i] = o;
    }
}

// ---------------------------------------------------------------------------
// gemm_lnbt: C[m,n] = sum_k LN(X)[m,k] * B[n,k]  (+bias[n]) (+relu)
// K = 512 fixed. A-tile = LN of 64 rows of f32 X, computed in prologue and
// resident in LDS (64x512 bf16, XOR-swizzled). B streamed BK=64, dbuf.
// Per-512-col part p = n0>>9 (iff B1 != nullptr): X/g/b select p==0 ? set0 : set1,
// B selects B0/B1/B2. Epilogue: nl >= vth -> vt[b][nl-vth][s]; else Cb.
// Dynamic LDS: 64*512*2 + 2*4096*2 = 81920 B.
// ---------------------------------------------------------------------------
__global__ __launch_bounds__(256) void gemm_lnbt(
    const float* __restrict__ X0, const float* __restrict__ X1,
    const float* __restrict__ g0p, const float* __restrict__ b0p,
    const float* __restrict__ g1p, const float* __restrict__ b1p,
    const u16* __restrict__ B0, const u16* __restrict__ B1,
    const u16* __restrict__ B2,
    u16* __restrict__ Cb, int csm,
    const float* __restrict__ bias, int relu,
    int vth, u16* vtp)
{
    extern __shared__ u16 lds[];
    u16* As  = lds;                 // 64*512
    u16* Bs0 = lds + 64 * 512;      // 4096
    u16* Bs1 = Bs0 + 4096;
    int mt, nt; swz_tile(mt, nt);
    const int m0 = mt << 6, n0 = nt << 6;
    const int t = threadIdx.x, lane = t & 63, wave = t >> 6;

    const int p = B1 ? (n0 >> 9) : 0;
    const float* X  = p ? X1 : X0;
    const float* gp = p ? g1p : g0p;
    const float* bp = p ? b1p : b0p;
    const u16* Bmat; int nb;
    if (B1) { Bmat = (p == 0) ? B0 : (p == 1 ? B1 : B2); nb = n0 & 511; }
    else    { Bmat = B0; nb = n0; }

    // ---- LN prologue: 4 threads per row ----
    const int rr = t >> 2, qq = t & 3;
    const float* xr = X + (long)(m0 + rr) * 512 + (qq << 7);
    float s = 0.f, ss = 0.f;
    #pragma unroll
    for (int i = 0; i < 32; i++) {
        float4 v = ((const float4*)xr)[i];
        s  += v.x + v.y + v.z + v.w;
        ss += v.x * v.x + v.y * v.y + v.z * v.z + v.w * v.w;
    }
    s  += __shfl_xor(s, 1);  s  += __shfl_xor(s, 2);
    ss += __shfl_xor(ss, 1); ss += __shfl_xor(ss, 2);
    const float mean = s * (1.f / 512.f);
    const float rstd = rsqrtf(fmaxf(ss * (1.f / 512.f) - mean * mean, 0.f) + LNEPS);
    #pragma unroll
    for (int i = 0; i < 32; i += 2) {
        float4 a = ((const float4*)xr)[i];
        float4 c = ((const float4*)xr)[i + 1];
        const int k0 = (qq << 7) + (i << 2);
        float4 ga = *(const float4*)&gp[k0], gc = *(const float4*)&gp[k0 + 4];
        float4 ba = *(const float4*)&bp[k0], bc = *(const float4*)&bp[k0 + 4];
        short8 o;
        o[0] = (short)f2bf((a.x - mean) * rstd * ga.x + ba.x);
        o[1] = (short)f2bf((a.y - mean) * rstd * ga.y + ba.y);
        o[2] = (short)f2bf((a.z - mean) * rstd * ga.z + ba.z);
        o[3] = (short)f2bf((a.w - mean) * rstd * ga.w + ba.w);
        o[4] = (short)f2bf((c.x - mean) * rstd * gc.x + bc.x);
        o[5] = (short)f2bf((c.y - mean) * rstd * gc.y + bc.y);
        o[6] = (short)f2bf((c.z - mean) * rstd * gc.z + bc.z);
        o[7] = (short)f2bf((c.w - mean) * rstd * gc.w + bc.w);
        const int ch = k0 >> 3;                       // global k-chunk 0..63
        *(short8*)&As[(rr << 9) + ((ch ^ (rr & 7)) << 3)] = o;
    }

    // ---- B staging (BK=64, dbuf) ----
    const int sr = t >> 3, sc = (t & 7) ^ (sr & 7);
    const u16* Bg0 = Bmat + (long)(nb + sr) * 512 + (sc << 3);
    const u16* Bg1 = Bg0 + 32L * 512;
    gl_lds16(Bg0, Bs0 + (t << 3));
    gl_lds16(Bg1, Bs0 + ((t + 256) << 3));
    __syncthreads();

    const int wr = (wave >> 1) << 5, wc = (wave & 1) << 5;
    const int fr = lane & 15, fq = lane >> 4;
    f32x4 acc[2][2];
    #pragma unroll
    for (int i = 0; i < 2; i++)
        #pragma unroll
        for (int j = 0; j < 2; j++) acc[i][j] = (f32x4){0.f, 0.f, 0.f, 0.f};

    for (int ki = 0; ki < 8; ki++) {
        u16* Bc = (ki & 1) ? Bs1 : Bs0;
        u16* Bn = (ki & 1) ? Bs0 : Bs1;
        if (ki + 1 < 8) {
            const int ko = (ki + 1) << 6;
            gl_lds16(Bg0 + ko, Bn + (t << 3));
            gl_lds16(Bg1 + ko, Bn + ((t + 256) << 3));
        }
        const int r0 = wr + fr, r1 = wr + 16 + fr;
        const int c0 = wc + fr, c1 = wc + 16 + fr;
        #pragma unroll
        for (int h = 0; h < 2; h++) {
            const int lc = fq | (h << 2);
            const int gA = (ki << 3) | lc;
            short8 af0 = *(const short8*)&As[(r0 << 9) + ((gA ^ (r0 & 7)) << 3)];
            short8 af1 = *(const short8*)&As[(r1 << 9) + ((gA ^ (r1 & 7)) << 3)];
            short8 bf0 = *(const short8*)&Bc[(c0 << 6) + ((lc ^ (c0 & 7)) << 3)];
            short8 bf1 = *(const short8*)&Bc[(c1 << 6) + ((lc ^ (c1 & 7)) << 3)];
            acc[0][0] = __builtin_amdgcn_mfma_f32_16x16x32_bf16(af0, bf0, acc[0][0], 0, 0, 0);
            acc[0][1] = __builtin_amdgcn_mfma_f32_16x16x32_bf16(af0, bf1, acc[0][1], 0, 0, 0);
            acc[1][0] = __builtin_amdgcn_mfma_f32_16x16x32_bf16(af1, bf0, acc[1][0], 0, 0, 0);
            acc[1][1] = __builtin_amdgcn_mfma_f32_16x16x32_bf16(af1, bf1, acc[1][1], 0, 0, 0);
        }
        __syncthreads();
    }

    #pragma unroll
    for (int i = 0; i < 2; i++) {
        #pragma unroll
        for (int j = 0; j < 2; j++) {
            const int nl  = n0 + wc + (j << 4) + fr;
            const int mlb = m0 + wr + (i << 4) + (fq << 2);
            const float bsv = bias ? bias[nl] : 0.f;
            #pragma unroll
            for (int r = 0; r < 4; r++) {
                const int ml = mlb + r;
                float v = acc[i][j][r] + bsv;
                if (nl >= vth) {
                    vtp[(long)(ml >> 9) * S2W + (long)(nl - vth) * 512 + (ml & 511)] = f2bf(v);
                } else {
                    if (relu) v = fmaxf(v, 0.f);
                    Cb[(long)ml * csm + nl] = f2bf(v);
                }
            }
        }
    }
}

// ---------------------------------------------------------------------------
// gemm_bt: C[m,n] = sum_k A[m,k]*B[n,k] (+bias[n]); bf16 A (no LN).
// 64x64 tile, BK=64, dbuf, one barrier per K-step. Split-K: grid.z slices of
// Kc; ns>1 -> unsafeAtomicAdd f32 into Cf (bias from slice 0 only).
// Used for Wo (splitK2) and FFN2 (splitK4).
// ---------------------------------------------------------------------------
__global__ __launch_bounds__(256) void gemm_bt(
    const u16* __restrict__ A0, int lda,
    const u16* __restrict__ B0, int ldb,
    float* Cf, int csm,
    const float* __restrict__ bias,
    int Kc, int ns)
{
    __shared__ u16 As[2][4096];   // 64 rows x 64 k
    __shared__ u16 Bs[2][4096];
    int mt, nt; swz_tile(mt, nt);
    const int m0 = mt << 6, n0 = nt << 6;
    const int t = threadIdx.x, lane = t & 63, wave = t >> 6;
    const int wr = (wave >> 1) << 5, wc = (wave & 1) << 5;
    const int fr = lane & 15, fq = lane >> 4;
    const int srow = t >> 3;
    const int sch  = (t & 7) ^ (srow & 7);
    const long kb = (long)blockIdx.z * Kc;

    const u16* Ag0 = A0 + (long)(m0 + srow) * lda + kb + (sch << 3);
    const u16* Ag1 = Ag0 + 32L * lda;
    const u16* Bg0 = B0 + (long)(n0 + srow) * ldb + kb + (sch << 3);
    const u16* Bg1 = Bg0 + 32L * ldb;

    f32x4 acc[2][2];
    #pragma unroll
    for (int i = 0; i < 2; i++)
        #pragma unroll
        for (int j = 0; j < 2; j++) acc[i][j] = (f32x4){0.f, 0.f, 0.f, 0.f};

    const int nk = Kc >> 6;
    gl_lds16(Ag0, &As[0][t << 3]);
    gl_lds16(Ag1, &As[0][(t + 256) << 3]);
    gl_lds16(Bg0, &Bs[0][t << 3]);
    gl_lds16(Bg1, &Bs[0][(t + 256) << 3]);
    __syncthreads();
    for (int ki = 0; ki < nk; ki++) {
        const int cur = ki & 1;
        if (ki + 1 < nk) {
            const int ko = (ki + 1) << 6;
            gl_lds16(Ag0 + ko, &As[cur ^ 1][t << 3]);
            gl_lds16(Ag1 + ko, &As[cur ^ 1][(t + 256) << 3]);
            gl_lds16(Bg0 + ko, &Bs[cur ^ 1][t << 3]);
            gl_lds16(Bg1 + ko, &Bs[cur ^ 1][(t + 256) << 3]);
        }
        const int r0 = wr + fr, r1 = wr + 16 + fr;
        const int c0 = wc + fr, c1 = wc + 16 + fr;
        #pragma unroll
        for (int h = 0; h < 2; h++) {
            const int lc = fq | (h << 2);
            short8 af0 = *(const short8*)&As[cur][(r0 << 6) + ((lc ^ (r0 & 7)) << 3)];
            short8 af1 = *(const short8*)&As[cur][(r1 << 6) + ((lc ^ (r1 & 7)) << 3)];
            short8 bf0 = *(const short8*)&Bs[cur][(c0 << 6) + ((lc ^ (c0 & 7)) << 3)];
            short8 bf1 = *(const short8*)&Bs[cur][(c1 << 6) + ((lc ^ (c1 & 7)) << 3)];
            acc[0][0] = __builtin_amdgcn_mfma_f32_16x16x32_bf16(af0, bf0, acc[0][0], 0, 0, 0);
            acc[0][1] = __builtin_amdgcn_mfma_f32_16x16x32_bf16(af0, bf1, acc[0][1], 0, 0, 0);
            acc[1][0] = __builtin_amdgcn_mfma_f32_16x16x32_bf16(af1, bf0, acc[1][0], 0, 0, 0);
            acc[1][1] = __builtin_amdgcn_mfma_f32_16x16x32_bf16(af1, bf1, acc[1][1], 0, 0, 0);
        }
        __syncthreads();
    }

    #pragma unroll
    for (int i = 0; i < 2; i++) {
        #pragma unroll
        for (int j = 0; j < 2; j++) {
            const int nl  = n0 + wc + (j << 4) + fr;
            const int mlb = m0 + wr + (i << 4) + (fq << 2);
            const float bsv = (bias && blockIdx.z == 0) ? bias[nl] : 0.f;
            #pragma unroll
            for (int r = 0; r < 4; r++) {
                const int ml = mlb + r;
                float v = acc[i][j][r] + bsv;
                if (ns > 1) unsafeAtomicAdd(&Cf[(long)ml * csm + nl], v);
                else        Cf[(long)ml * csm + nl] = v;
            }
        }
    }
}

// ---------------------------------------------------------------------------
// gemm_big: 128x128 tile, BK=64, dbuf, one barrier per K-step; chunk swizzle
// c^(r&7). Logits GEMM only. Dynamic LDS 65536 B.
// ---------------------------------------------------------------------------
__global__ __launch_bounds__(256) void gemm_big(
    const u16* __restrict__ A, int lda,
    const u16* __restrict__ B, int ldb,
    float* Cf, int ldc,
    const float* __restrict__ bias, int K)
{
    extern __shared__ u16 lds[];
    u16* As0 = lds;            // 128*64
    u16* As1 = lds + 8192;
    u16* Bs0 = lds + 16384;
    u16* Bs1 = lds + 24576;
    int mt, nt; swz_tile(mt, nt);
    const int m0 = mt << 7, n0 = nt << 7;
    const int t = threadIdx.x, lane = t & 63, wave = t >> 6;
    const int wr = (wave >> 1) << 6, wc = (wave & 1) << 6;
    const int fr = lane & 15, fq = lane >> 4;
    const int sr = t >> 3;
    const int sc = (t & 7) ^ (sr & 7);
    const u16* Ag0 = A + (long)(m0 + sr) * lda + (sc << 3);
    const u16* Ag1 = Ag0 + 32L * lda;
    const u16* Ag2 = Ag0 + 64L * lda;
    const u16* Ag3 = Ag0 + 96L * lda;
    const u16* Bg0 = B + (long)(n0 + sr) * ldb + (sc << 3);
    const u16* Bg1 = Bg0 + 32L * ldb;
    const u16* Bg2 = Bg0 + 64L * ldb;
    const u16* Bg3 = Bg0 + 96L * ldb;

    f32x4 acc[4][4];
    #pragma unroll
    for (int i = 0; i < 4; i++)
        #pragma unroll
        for (int j = 0; j < 4; j++) acc[i][j] = (f32x4){0.f, 0.f, 0.f, 0.f};

    const int nk = K >> 6;
    {
        gl_lds16(Ag0, As0 + (t << 3));
        gl_lds16(Ag1, As0 + ((t + 256) << 3));
        gl_lds16(Ag2, As0 + ((t + 512) << 3));
        gl_lds16(Ag3, As0 + ((t + 768) << 3));
        gl_lds16(Bg0, Bs0 + (t << 3));
        gl_lds16(Bg1, Bs0 + ((t + 256) << 3));
        gl_lds16(Bg2, Bs0 + ((t + 512) << 3));
        gl_lds16(Bg3, Bs0 + ((t + 768) << 3));
    }
    __syncthreads();
    for (int ki = 0; ki < nk; ki++) {
        u16* Ac = (ki & 1) ? As1 : As0;
        u16* Bc = (ki & 1) ? Bs1 : Bs0;
        u16* An = (ki & 1) ? As0 : As1;
        u16* Bn = (ki & 1) ? Bs0 : Bs1;
        if (ki + 1 < nk) {
            const int ko = (ki + 1) << 6;
            gl_lds16(Ag0 + ko, An + (t << 3));
            gl_lds16(Ag1 + ko, An + ((t + 256) << 3));
            gl_lds16(Ag2 + ko, An + ((t + 512) << 3));
            gl_lds16(Ag3 + ko, An + ((t + 768) << 3));
            gl_lds16(Bg0 + ko, Bn + (t << 3));
            gl_lds16(Bg1 + ko, Bn + ((t + 256) << 3));
            gl_lds16(Bg2 + ko, Bn + ((t + 512) << 3));
            gl_lds16(Bg3 + ko, Bn + ((t + 768) << 3));
        }
        #pragma unroll
        for (int h = 0; h < 2; h++) {
            const int lc = fq | (h << 2);
            short8 af[4], bf[4];
            #pragma unroll
            for (int i = 0; i < 4; i++) {
                const int r = wr + (i << 4) + fr;
                af[i] = *(const short8*)&Ac[(r << 6) + ((lc ^ (r & 7)) << 3)];
            }
            #pragma unroll
            for (int j = 0; j < 4; j++) {
                const int c = wc + (j << 4) + fr;
                bf[j] = *(const short8*)&Bc[(c << 6) + ((lc ^ (c & 7)) << 3)];
            }
            #pragma unroll
            for (int i = 0; i < 4; i++)
                #pragma unroll
                for (int j = 0; j < 4; j++)
                    acc[i][j] = __builtin_amdgcn_mfma_f32_16x16x32_bf16(af[i], bf[j], acc[i][j], 0, 0, 0);
        }
        __syncthreads();
    }

    #pragma unroll
    for (int i = 0; i < 4; i++) {
        #pragma unroll
        for (int j = 0; j < 4; j++) {
            const int nl  = n0 + wc + (j << 4) + fr;
            const int mlb = m0 + wr + (i << 4) + (fq << 2);
            const float bsv = bias ? bias[nl] : 0.f;
            #pragma unroll
            for (int r = 0; r < 4; r++)
                Cf[(long)(mlb + r) * ldc + nl] = acc[i][j][r] + bsv;
        }
    }
}

// ---------------------------------------------------------------------------
// Fused attention: block per (q-tile 64, head, batch), 4 waves x 16 q-rows.
// K/V tiles in LDS, double-buffered, one barrier per tile; sources
// pre-swizzled (c' = c ^ (row&7)) so swizzled ds_reads are conflict-free.
// ---------------------------------------------------------------------------
__global__ __launch_bounds__(256) void attn_fused(
    const u16* __restrict__ qkb, const u16* __restrict__ vt,
    const int* __restrict__ ids, u16* __restrict__ attc, int causal)
{
    __shared__ u16 Ks[2][4096];
    __shared__ u16 Vs[2][4096];
    __shared__ short Ps[4][16][72];
    const int t = threadIdx.x, lane = t & 63, w = t >> 6;
    const int fr = lane & 15, fq = lane >> 4;
    const int q0 = blockIdx.x << 6, h = blockIdx.y, b = blockIdx.z;

    const u16* qp = qkb + (long)(b * 512 + q0 + (w << 4) + fr) * 1024 + h * 64 + (fq << 3);
    short8 aq0 = *(const short8*)qp;
    short8 aq1 = *(const short8*)(qp + 32);

    const int sr = t >> 3, sc = (t & 7) ^ (sr & 7);
    const u16* kg0 = qkb + (long)(b * 512 + sr) * 1024 + 512 + h * 64 + (sc << 3);
    const u16* kg1 = kg0 + 32L * 1024;
    const u16* vg0 = vt + (long)b * S2W + (long)(h * 64 + sr) * 512 + (sc << 3);
    const u16* vg1 = vg0 + 32L * 512;

    unsigned pmask = 0;
    #pragma unroll
    for (int kt = 0; kt < 8; kt++)
        #pragma unroll
        for (int j = 0; j < 4; j++)
            if (ids[b * 512 + (kt << 6) + (j << 4) + fr] == PADID)
                pmask |= 1u << ((kt << 2) + j);

    float m[4], l[4]; f32x4 oc[4];
    #pragma unroll
    for (int r = 0; r < 4; r++) { m[r] = -INFINITY; l[r] = 0.f; oc[r] = (f32x4){0.f,0.f,0.f,0.f}; }

    const int lastkt = causal ? (q0 >> 6) : 7;
    auto stage = [&](int kt, int buf) {
        const long so = (long)(kt << 6);
        gl_lds16(kg0 + so * 1024, &Ks[buf][t << 3]);
        gl_lds16(kg1 + so * 1024, &Ks[buf][(t + 256) << 3]);
        gl_lds16(vg0 + so, &Vs[buf][t << 3]);
        gl_lds16(vg1 + so, &Vs[buf][(t + 256) << 3]);
    };
    stage(0, 0);
    __syncthreads();

    for (int kt = 0; kt <= lastkt; kt++) {
        const int cur = kt & 1;
        if (kt < lastkt) stage(kt + 1, cur ^ 1);

        f32x4 sc4[4];
        #pragma unroll
        for (int j = 0; j < 4; j++) sc4[j] = (f32x4){0.f,0.f,0.f,0.f};
        #pragma unroll
        for (int j = 0; j < 4; j++) {
            const int rr = (j << 4) + fr;
            short8 bk0 = *(const short8*)&Ks[cur][rr * 64 + ((fq ^ (rr & 7)) << 3)];
            short8 bk1 = *(const short8*)&Ks[cur][rr * 64 + (((fq | 4) ^ (rr & 7)) << 3)];
            sc4[j] = __builtin_amdgcn_mfma_f32_16x16x32_bf16(aq0, bk0, sc4[j], 0, 0, 0);
            sc4[j] = __builtin_amdgcn_mfma_f32_16x16x32_bf16(aq1, bk1, sc4[j], 0, 0, 0);
        }
        const int s0 = kt << 6;
        #pragma unroll
        for (int r = 0; r < 4; r++) {
            const int qa = q0 + (w << 4) + (fq << 2) + r;
            float mx = -INFINITY;
            #pragma unroll
            for (int j = 0; j < 4; j++) {
                bool msk = ((pmask >> ((kt << 2) + j)) & 1) ||
                           (causal && (s0 + (j << 4) + fr) > qa);
                float sv = msk ? -INFINITY : sc4[j][r] * 0.125f;
                sc4[j][r] = sv;
                mx = fmaxf(mx, sv);
            }
            mx = fmaxf(mx, __shfl_xor(mx, 1)); mx = fmaxf(mx, __shfl_xor(mx, 2));
            mx = fmaxf(mx, __shfl_xor(mx, 4)); mx = fmaxf(mx, __shfl_xor(mx, 8));
            float mnew  = fmaxf(m[r], mx);
            float scale = (mnew == -INFINITY) ? 1.f : __expf(m[r] - mnew);
            float ps = 0.f;
            #pragma unroll
            for (int j = 0; j < 4; j++) {
                float p = (sc4[j][r] == -INFINITY) ? 0.f : __expf(sc4[j][r] - mnew);
                sc4[j][r] = p; ps += p;
            }
            ps += __shfl_xor(ps, 1); ps += __shfl_xor(ps, 2);
            ps += __shfl_xor(ps, 4); ps += __shfl_xor(ps, 8);
            l[r] = l[r] * scale + ps;
            m[r] = mnew;
            #pragma unroll
            for (int j2 = 0; j2 < 4; j2++) oc[j2][r] *= scale;
        }
        #pragma unroll
        for (int r = 0; r < 4; r++)
            #pragma unroll
            for (int j = 0; j < 4; j++)
                Ps[w][(fq << 2) + r][(j << 4) + fr] = (short)f2bf(sc4[j][r]);
        #pragma unroll
        for (int kc = 0; kc < 2; kc++) {
            short8 pa = *(const short8*)&Ps[w][fr][(kc << 5) + (fq << 3)];
            #pragma unroll
            for (int j2 = 0; j2 < 4; j2++) {
                const int rd = (j2 << 4) + fr;
                const int cch = (((kc << 2) | fq) ^ (rd & 7));
                short8 bv = *(const short8*)&Vs[cur][rd * 64 + (cch << 3)];
                oc[j2] = __builtin_amdgcn_mfma_f32_16x16x32_bf16(pa, bv, oc[j2], 0, 0, 0);
            }
        }
        __syncthreads();
    }

    float inv[4];
    #pragma unroll
    for (int r = 0; r < 4; r++) inv[r] = (l[r] > 0.f) ? 1.f / l[r] : 0.f;
    #pragma unroll
    for (int j2 = 0; j2 < 4; j2++)
        #pragma unroll
        for (int r = 0; r < 4; r++)
            attc[(long)(b * 512 + q0 + (w << 4) + (fq << 2) + r) * 512 + h * 64 + (j2 << 4) + fr]
                = f2bf(oc[j2][r] * inv[r]);
}

// LayerNorm over D=512: 4 rows/block (wave per row). f32 in -> bf16 out.
__global__ __launch_bounds__(256) void ln_rows(
    const float* __restrict__ x, const float* __restrict__ g,
    const float* __restrict__ b, u16* __restrict__ out)
{
    int row  = blockIdx.x * 4 + (threadIdx.x >> 6);
    int lane = threadIdx.x & 63;
    const float* xr = x + (long)row * Dm;
    float v[8]; float s = 0.f;
    #pragma unroll
    for (int i = 0; i < 8; i++) { v[i] = xr[lane + (i << 6)]; s += v[i]; }
    #pragma unroll
    for (int o = 32; o > 0; o >>= 1) s += __shfl_xor(s, o);
    float mean = s * (1.f / 512.f);
    float q = 0.f;
    #pragma unroll
    for (int i = 0; i < 8; i++) { float d = v[i] - mean; q += d * d; }
    #pragma unroll
    for (int o = 32; o > 0; o >>= 1) q += __shfl_xor(q, o);
    float rinv = rsqrtf(q * (1.f / 512.f) + LNEPS);
    u16* orow = out + (long)row * Dm;
    #pragma unroll
    for (int i = 0; i < 8; i++) {
        int c = lane + (i << 6);
        orow[c] = f2bf((v[i] - mean) * rinv * g[c] + b[c]);
    }
}

// x[b,s,:] = embed[id]*sqrt(D) + PE(s,:)   (f32 in/out)
__global__ __launch_bounds__(256) void embed_pe(
    const int* __restrict__ ids, const float* __restrict__ emb,
    float* __restrict__ out)
{
    int idx = blockIdx.x * 256 + threadIdx.x;   // NTOK*512 = 2^20
    int d   = idx & 511;
    int tok = idx >> 9;
    int s   = tok & 511;
    int id  = ids[tok];
    float val = emb[(long)id * Dm + d] * 22.62741699796952f;     // sqrt(512)
    int i2 = d >> 1;
    float dv  = expf((float)(i2 << 1) * (-9.210340371976184f / 512.f));
    float ang = (float)s * dv;
    val += (d & 1) ? cosf(ang) : sinf(ang);
    out[idx] = val;
}

// ---------------------------------------------------------------------------
extern "C" void kernel_launch(void* const* d_in, const int* in_sizes, int n_in,
                              void* d_out, int out_size, void* d_ws, size_t ws_size,
                              hipStream_t stream)
{
    (void)in_sizes; (void)n_in; (void)out_size; (void)ws_size;
    const int*   src       = (const int*)d_in[0];
    const int*   tgt       = (const int*)d_in[1];
    const float* src_embed = (const float*)d_in[2];
    const float* tgt_embed = (const float*)d_in[3];
    const float* enc_b1  = (const float*)d_in[9];
    const float* enc_b2  = (const float*)d_in[11];
    const float* enc_ln1g = (const float*)d_in[12];
    const float* enc_ln1b = (const float*)d_in[13];
    const float* enc_ln2g = (const float*)d_in[14];
    const float* enc_ln2b = (const float*)d_in[15];
    const float* enc_lnfg = (const float*)d_in[16];
    const float* enc_lnfb = (const float*)d_in[17];
    const float* dec_b1  = (const float*)d_in[27];
    const float* dec_b2  = (const float*)d_in[29];
    const float* dec_ln1g = (const float*)d_in[30];
    const float* dec_ln1b = (const float*)d_in[31];
    const float* dec_ln2g = (const float*)d_in[32];
    const float* dec_ln2b = (const float*)d_in[33];
    const float* dec_ln3g = (const float*)d_in[34];
    const float* dec_ln3b = (const float*)d_in[35];
    const float* dec_lnfg = (const float*)d_in[36];
    const float* dec_lnfb = (const float*)d_in[37];
    const float* out_b  = (const float*)d_in[39];

    char* wp = (char*)d_ws;
    auto carve = [&](size_t nbytes) {
        void* p = (void*)wp; wp += (nbytes + 255) & ~(size_t)255; return p;
    };

    const long nW = (long)NLay * S2W;
    const long nF = (long)NLay * DFFm * Dm;
    const long nO = 32000L * Dm;

    u16* Wb[12];
    for (int i = 0; i < 12; i++) Wb[i] = (u16*)carve((size_t)nW * 2);
    u16* w1E  = (u16*)carve((size_t)nF * 2);
    u16* w2E  = (u16*)carve((size_t)nF * 2);
    u16* w1D  = (u16*)carve((size_t)nF * 2);
    u16* w2D  = (u16*)carve((size_t)nF * 2);
    u16* outW = (u16*)carve((size_t)nO * 2);

    float* x  = (float*)carve((size_t)NTOK * Dm * 4);
    float* y  = (float*)carve((size_t)NTOK * Dm * 4);
    u16* nrm  = (u16*)carve((size_t)NTOK * Dm * 2);
    u16* qkb  = (u16*)carve((size_t)NTOK * 1024 * 2);
    u16* vt   = (u16*)carve((size_t)Bb * Dm * 512 * 2);
    u16* attc = (u16*)carve((size_t)NTOK * Dm * 2);
    u16* h1   = (u16*)carve((size_t)NTOK * DFFm * 2);

    // d_in indices for the 12 attn weight tensors, matching Wb order:
    // eWq eWk eWv eWo | sWq sWk sWv sWo | cWq cWk cWv cWo
    const int wi[12] = {4, 5, 6, 7, 18, 19, 20, 21, 22, 23, 24, 25};
    CvtJobs jobs;
    for (int i = 0; i < 12; i++) {
        jobs.s[i] = (const float*)d_in[wi[i]]; jobs.d[i] = Wb[i]; jobs.n4[i] = nW >> 2;
    }
    jobs.s[12] = (const float*)d_in[8];  jobs.d[12] = w1E;  jobs.n4[12] = nF >> 2;
    jobs.s[13] = (const float*)d_in[10]; jobs.d[13] = w2E;  jobs.n4[13] = nF >> 2;
    jobs.s[14] = (const float*)d_in[26]; jobs.d[14] = w1D;  jobs.n4[14] = nF >> 2;
    jobs.s[15] = (const float*)d_in[28]; jobs.d[15] = w2D;  jobs.n4[15] = nF >> 2;
    jobs.s[16] = (const float*)d_in[38]; jobs.d[16] = outW; jobs.n4[16] = nO >> 2;
    cvt_many<<<dim3(512, 17), 256, 0, stream>>>(jobs);

    const int BIG = 1 << 28;
    u16 *eWq = Wb[0], *eWk = Wb[1], *eWv = Wb[2], *eWo = Wb[3];
    u16 *sWq = Wb[4], *sWk = Wb[5], *sWv = Wb[6], *sWo = Wb[7];
    u16 *cWq = Wb[8], *cWk = Wb[9], *cWv = Wb[10], *cWo = Wb[11];

    const size_t LNB = 64 * 512 * 2 + 2 * 4096 * 2;   // 81920 B
    const size_t BGB = 4 * 8192 * 2;                  // 65536 B

    // ---------------- Encoder ----------------
    embed_pe<<<4096, 256, 0, stream>>>(src, src_embed, x);
    for (int l = 0; l < NLay; l++) {
        const size_t wo = (size_t)l * S2W;
        // QKV with fused LN(ln1): qkb[:,0:512]=Q, [:,512:1024]=K, vt=V^T
        gemm_lnbt<<<dim3(24, 32), 256, LNB, stream>>>(
            x, x, enc_ln1g + l * Dm, enc_ln1b + l * Dm, enc_ln1g + l * Dm, enc_ln1b + l * Dm,
            eWq + wo, eWk + wo, eWv + wo, qkb, 1024, nullptr, 0, 1024, vt);
        attn_fused<<<dim3(8, Hh, Bb), 256, 0, stream>>>(qkb, vt, src, attc, 0);
        // x += attc @ Wo^T (splitK2, atomic)
        gemm_bt<<<dim3(8, 32, 2), 256, 0, stream>>>(attc, 512, eWo + wo, 512,
            x, 512, nullptr, 256, 2);
        // h1 = relu(LN(x,ln2) @ w1^T + b1)
        gemm_lnbt<<<dim3(32, 32), 256, LNB, stream>>>(
            x, x, enc_ln2g + l * Dm, enc_ln2b + l * Dm, enc_ln2g + l * Dm, enc_ln2b + l * Dm,
            w1E + (size_t)l * DFFm * Dm, nullptr, nullptr, h1, DFFm,
            enc_b1 + l * DFFm, 1, BIG, nullptr);
        // x += h1 @ w2^T + b2 (splitK4, atomic)
        gemm_bt<<<dim3(8, 32, 4), 256, 0, stream>>>(h1, DFFm, w2E + (size_t)l * Dm * DFFm, DFFm,
            x, 512, enc_b2 + l * Dm, 512, 4);
    }
    // (final encoder LN is recomputed inside each decoder cross-QKV dispatch)

    // ---------------- Decoder ----------------
    embed_pe<<<4096, 256, 0, stream>>>(tgt, tgt_embed, y);
    for (int l = 0; l < NLay; l++) {
        const size_t wo = (size_t)l * S2W;
        // self-attention (causal + tgt pad), LN(ln1) fused
        gemm_lnbt<<<dim3(24, 32), 256, LNB, stream>>>(
            y, y, dec_ln1g + l * Dm, dec_ln1b + l * Dm, dec_ln1g + l * Dm, dec_ln1b + l * Dm,
            sWq + wo, sWk + wo, sWv + wo, qkb, 1024, nullptr, 0, 1024, vt);
        attn_fused<<<dim3(8, Hh, Bb), 256, 0, stream>>>(qkb, vt, tgt, attc, 1);
        gemm_bt<<<dim3(8, 32, 2), 256, 0, stream>>>(attc, 512, sWo + wo, 512,
            y, 512, nullptr, 256, 2);
        // cross-attention: Q from LN(y,ln2); K,V from LN(x_enc,lnfE)
        gemm_lnbt<<<dim3(24, 32), 256, LNB, stream>>>(
            y, x, dec_ln2g + l * Dm, dec_ln2b + l * Dm, enc_lnfg, enc_lnfb,
            cWq + wo, cWk + wo, cWv + wo, qkb, 1024, nullptr, 0, 1024, vt);
        attn_fused<<<dim3(8, Hh, Bb), 256, 0, stream>>>(qkb, vt, src, attc, 0);
        gemm_bt<<<dim3(8, 32, 2), 256, 0, stream>>>(attc, 512, cWo + wo, 512,
            y, 512, nullptr, 256, 2);
        // FFN with fused LN(ln3)
        gemm_lnbt<<<dim3(32, 32), 256, LNB, stream>>>(
            y, y, dec_ln3g + l * Dm, dec_ln3b + l * Dm, dec_ln3g + l * Dm, dec_ln3b + l * Dm,
            w1D + (size_t)l * DFFm * Dm, nullptr, nullptr, h1, DFFm,
            dec_b1 + l * DFFm, 1, BIG, nullptr);
        gemm_bt<<<dim3(8, 32, 4), 256, 0, stream>>>(h1, DFFm, w2D + (size_t)l * Dm * DFFm, DFFm,
            y, 512, dec_b2 + l * Dm, 512, 4);
    }
    ln_rows<<<512, 256, 0, stream>>>(y, dec_lnfg, dec_lnfb, nrm);

    // final projection to vocab: [2048][32000] f32 out
    gemm_big<<<dim3(250, 16), 256, BGB, stream>>>(nrm, 512, outW, 512,
        (float*)d_out, 32000, out_b, 512);
}

// Round 9
// 3044.837 us; speedup vs baseline: 1.1879x; 1.1879x over previous
//
#include <hip/hip_runtime.h>
#include <hip/hip_bf16.h>
#include <math.h>

// ---------------- problem constants ----------------
#define Dm    512
#define Hh    8
#define NLay  6
#define DFFm  2048
#define Bb    4
#define NTOK  2048          // B * S
#define PADID 1
#define LNEPS 1e-5f
#define S2W   262144        // 512*512 elements (one [512][512] plane)

typedef __attribute__((ext_vector_type(8))) short short8;   // 8 x bf16 (4 VGPRs)
typedef __attribute__((ext_vector_type(4))) float f32x4;
typedef unsigned short u16;

__device__ __forceinline__ u16 f2bf(float f) {
    union { float f; unsigned int i; } x; x.f = f;
    unsigned int r = x.i + 0x7fffu + ((x.i >> 16) & 1u);   // RNE
    return (u16)(r >> 16);
}

// async global->LDS, 16B per lane (dest must be linear-in-lane: base+lane*16)
typedef const __attribute__((address_space(1))) void* as1cv;
typedef __attribute__((address_space(3))) void* as3v;
__device__ __forceinline__ void gl_lds16(const u16* g, u16* l) {
    __builtin_amdgcn_global_load_lds((as1cv)g, (as3v)l, 16, 0, 0);
}

// bijective XCD-chunk swizzle (m204), M fastest within an XCD's chunk so
// consecutive wgids on one XCD share the B panel (its private L2).
__device__ __forceinline__ void swz_tile(int& mt, int& nt) {
    const int nwg  = gridDim.x * gridDim.y;
    const int orig = blockIdx.y * gridDim.x + blockIdx.x;
    const int q8 = nwg >> 3, r8 = nwg & 7;
    const int xcd = orig & 7, idx = orig >> 3;
    const int wgid = (xcd < r8 ? xcd * (q8 + 1) : r8 * (q8 + 1) + (xcd - r8) * q8) + idx;
    const int MT = gridDim.y;
    mt = wgid % MT;
    nt = wgid / MT;
}

// ---- one-launch f32->bf16 conversion of all 17 weight tensors ----
struct CvtJobs {
    const float* s[17];
    u16*         d[17];
    long         n4[17];
};
__global__ __launch_bounds__(256) void cvt_many(CvtJobs j) {
    const int job = blockIdx.y;
    const long n4 = j.n4[job];
    const float* in = j.s[job];
    u16* out = j.d[job];
    long i = (long)blockIdx.x * 256 + threadIdx.x;
    const long stride = (long)gridDim.x * 256;
    for (; i < n4; i += stride) {
        float4 v = ((const float4*)in)[i];
        ushort4 o;
        o.x = f2bf(v.x); o.y = f2bf(v.y); o.z = f2bf(v.z); o.w = f2bf(v.w);
        ((ushort4*)out)[i] = o;
    }
}

// ---------------------------------------------------------------------------
// gemm_lnbt v2: C[m,n] = sum_k LN(X)[m,k] * B[n,k]  (+bias[n]) (+relu)
// K = 512 fixed. A-tile = LN of 64 rows of f32 X, resident in LDS
// (64x512 bf16, chunk swizzle ch^(r&7)). B streamed BK=32, dbuf
// (chunk swizzle c^((r>>1)&3)). B-stage for both buffers ISSUED BEFORE the
// LN prologue (HBM latency hides under LN compute). Unrolls capped to avoid
// register spill. Dynamic LDS: 64*512*2 + 2*2048*2 = 73728 B (2 blocks/CU).
// Per-512-col part p = n0>>9 (iff B1 != nullptr): X/g/b select set0/set1,
// B selects B0/B1/B2. Epilogue: nl >= vth -> vt[b][nl-vth][s]; else Cb.
// ---------------------------------------------------------------------------
__global__ __launch_bounds__(256) void gemm_lnbt(
    const float* __restrict__ X0, const float* __restrict__ X1,
    const float* __restrict__ g0p, const float* __restrict__ b0p,
    const float* __restrict__ g1p, const float* __restrict__ b1p,
    const u16* __restrict__ B0, const u16* __restrict__ B1,
    const u16* __restrict__ B2,
    u16* __restrict__ Cb, int csm,
    const float* __restrict__ bias, int relu,
    int vth, u16* vtp)
{
    extern __shared__ u16 lds[];
    u16* As  = lds;                 // 64*512
    u16* Bs0 = lds + 64 * 512;      // 64n x 32k = 2048 u16
    u16* Bs1 = Bs0 + 2048;
    int mt, nt; swz_tile(mt, nt);
    const int m0 = mt << 6, n0 = nt << 6;
    const int t = threadIdx.x, lane = t & 63, wave = t >> 6;

    const int p = B1 ? (n0 >> 9) : 0;
    const float* X  = p ? X1 : X0;
    const float* gp = p ? g1p : g0p;
    const float* bp = p ? b1p : b0p;
    const u16* Bmat; int nb;
    if (B1) { Bmat = (p == 0) ? B0 : (p == 1 ? B1 : B2); nb = n0 & 511; }
    else    { Bmat = B0; nb = n0; }

    // ---- B stage issue FIRST: buffers 0 and 1 in flight during LN ----
    const int sr = t >> 2, scB = (t & 3) ^ ((sr >> 1) & 3);
    const u16* Bg = Bmat + (long)(nb + sr) * 512 + (scB << 3);
    gl_lds16(Bg,      Bs0 + (t << 3));
    gl_lds16(Bg + 32, Bs1 + (t << 3));

    // ---- LN prologue: 4 threads per row, capped unroll (no spill) ----
    const int rr = t >> 2, qq = t & 3;
    const float* xr = X + (long)(m0 + rr) * 512 + (qq << 7);
    float s = 0.f, ss = 0.f;
    #pragma unroll 4
    for (int i = 0; i < 32; i++) {
        float4 v = ((const float4*)xr)[i];
        s  += v.x + v.y + v.z + v.w;
        ss += v.x * v.x + v.y * v.y + v.z * v.z + v.w * v.w;
    }
    s  += __shfl_xor(s, 1);  s  += __shfl_xor(s, 2);
    ss += __shfl_xor(ss, 1); ss += __shfl_xor(ss, 2);
    const float mean = s * (1.f / 512.f);
    const float rstd = rsqrtf(fmaxf(ss * (1.f / 512.f) - mean * mean, 0.f) + LNEPS);
    #pragma unroll 2
    for (int i = 0; i < 32; i += 2) {
        float4 a = ((const float4*)xr)[i];
        float4 c = ((const float4*)xr)[i + 1];
        const int k0 = (qq << 7) + (i << 2);
        float4 ga = *(const float4*)&gp[k0], gc = *(const float4*)&gp[k0 + 4];
        float4 ba = *(const float4*)&bp[k0], bc = *(const float4*)&bp[k0 + 4];
        short8 o;
        o[0] = (short)f2bf((a.x - mean) * rstd * ga.x + ba.x);
        o[1] = (short)f2bf((a.y - mean) * rstd * ga.y + ba.y);
        o[2] = (short)f2bf((a.z - mean) * rstd * ga.z + ba.z);
        o[3] = (short)f2bf((a.w - mean) * rstd * ga.w + ba.w);
        o[4] = (short)f2bf((c.x - mean) * rstd * gc.x + bc.x);
        o[5] = (short)f2bf((c.y - mean) * rstd * gc.y + bc.y);
        o[6] = (short)f2bf((c.z - mean) * rstd * gc.z + bc.z);
        o[7] = (short)f2bf((c.w - mean) * rstd * gc.w + bc.w);
        const int ch = k0 >> 3;                       // global k-chunk 0..63
        *(short8*)&As[(rr << 9) + ((ch ^ (rr & 7)) << 3)] = o;
    }
    __syncthreads();   // As ready; Bs0/Bs1 drained (barrier vmcnt0)

    const int wr = (wave >> 1) << 5, wc = (wave & 1) << 5;
    const int fr = lane & 15, fq = lane >> 4;
    f32x4 acc[2][2];
    #pragma unroll
    for (int i = 0; i < 2; i++)
        #pragma unroll
        for (int j = 0; j < 2; j++) acc[i][j] = (f32x4){0.f, 0.f, 0.f, 0.f};

    const int r0 = wr + fr, r1 = wr + 16 + fr;
    const int c0 = wc + fr, c1 = wc + 16 + fr;
    const int sB0 = (c0 << 5) + ((fq ^ ((c0 >> 1) & 3)) << 3);
    const int sB1 = (c1 << 5) + ((fq ^ ((c1 >> 1) & 3)) << 3);
    for (int ki = 0; ki < 16; ki++) {
        u16* Bc = (ki & 1) ? Bs1 : Bs0;
        const int gA = (ki << 2) | fq;
        short8 af0 = *(const short8*)&As[(r0 << 9) + ((gA ^ (r0 & 7)) << 3)];
        short8 af1 = *(const short8*)&As[(r1 << 9) + ((gA ^ (r1 & 7)) << 3)];
        short8 bf0 = *(const short8*)&Bc[sB0];
        short8 bf1 = *(const short8*)&Bc[sB1];
        acc[0][0] = __builtin_amdgcn_mfma_f32_16x16x32_bf16(af0, bf0, acc[0][0], 0, 0, 0);
        acc[0][1] = __builtin_amdgcn_mfma_f32_16x16x32_bf16(af0, bf1, acc[0][1], 0, 0, 0);
        acc[1][0] = __builtin_amdgcn_mfma_f32_16x16x32_bf16(af1, bf0, acc[1][0], 0, 0, 0);
        acc[1][1] = __builtin_amdgcn_mfma_f32_16x16x32_bf16(af1, bf1, acc[1][1], 0, 0, 0);
        __syncthreads();                               // done reading Bc
        if (ki + 2 < 16) gl_lds16(Bg + ((ki + 2) << 5), Bc + (t << 3));
    }

    #pragma unroll
    for (int i = 0; i < 2; i++) {
        #pragma unroll
        for (int j = 0; j < 2; j++) {
            const int nl  = n0 + wc + (j << 4) + fr;
            const int mlb = m0 + wr + (i << 4) + (fq << 2);
            const float bsv = bias ? bias[nl] : 0.f;
            #pragma unroll
            for (int r = 0; r < 4; r++) {
                const int ml = mlb + r;
                float v = acc[i][j][r] + bsv;
                if (nl >= vth) {
                    vtp[(long)(ml >> 9) * S2W + (long)(nl - vth) * 512 + (ml & 511)] = f2bf(v);
                } else {
                    if (relu) v = fmaxf(v, 0.f);
                    Cb[(long)ml * csm + nl] = f2bf(v);
                }
            }
        }
    }
}

// ---------------------------------------------------------------------------
// gemm_bt: C[m,n] = sum_k A[m,k]*B[n,k] (+bias[n]); bf16 A (no LN).
// 64x64 tile, BK=64, dbuf, one barrier per K-step. Split-K: grid.z slices of
// Kc; ns>1 -> unsafeAtomicAdd f32 into Cf (bias from slice 0 only).
// Used for Wo (splitK2) and FFN2 (splitK4).
// ---------------------------------------------------------------------------
__global__ __launch_bounds__(256) void gemm_bt(
    const u16* __restrict__ A0, int lda,
    const u16* __restrict__ B0, int ldb,
    float* Cf, int csm,
    const float* __restrict__ bias,
    int Kc, int ns)
{
    __shared__ u16 As[2][4096];   // 64 rows x 64 k
    __shared__ u16 Bs[2][4096];
    int mt, nt; swz_tile(mt, nt);
    const int m0 = mt << 6, n0 = nt << 6;
    const int t = threadIdx.x, lane = t & 63, wave = t >> 6;
    const int wr = (wave >> 1) << 5, wc = (wave & 1) << 5;
    const int fr = lane & 15, fq = lane >> 4;
    const int srow = t >> 3;
    const int sch  = (t & 7) ^ (srow & 7);
    const long kb = (long)blockIdx.z * Kc;

    const u16* Ag0 = A0 + (long)(m0 + srow) * lda + kb + (sch << 3);
    const u16* Ag1 = Ag0 + 32L * lda;
    const u16* Bg0 = B0 + (long)(n0 + srow) * ldb + kb + (sch << 3);
    const u16* Bg1 = Bg0 + 32L * ldb;

    f32x4 acc[2][2];
    #pragma unroll
    for (int i = 0; i < 2; i++)
        #pragma unroll
        for (int j = 0; j < 2; j++) acc[i][j] = (f32x4){0.f, 0.f, 0.f, 0.f};

    const int nk = Kc >> 6;
    gl_lds16(Ag0, &As[0][t << 3]);
    gl_lds16(Ag1, &As[0][(t + 256) << 3]);
    gl_lds16(Bg0, &Bs[0][t << 3]);
    gl_lds16(Bg1, &Bs[0][(t + 256) << 3]);
    __syncthreads();
    for (int ki = 0; ki < nk; ki++) {
        const int cur = ki & 1;
        if (ki + 1 < nk) {
            const int ko = (ki + 1) << 6;
            gl_lds16(Ag0 + ko, &As[cur ^ 1][t << 3]);
            gl_lds16(Ag1 + ko, &As[cur ^ 1][(t + 256) << 3]);
            gl_lds16(Bg0 + ko, &Bs[cur ^ 1][t << 3]);
            gl_lds16(Bg1 + ko, &Bs[cur ^ 1][(t + 256) << 3]);
        }
        const int r0 = wr + fr, r1 = wr + 16 + fr;
        const int c0 = wc + fr, c1 = wc + 16 + fr;
        #pragma unroll
        for (int h = 0; h < 2; h++) {
            const int lc = fq | (h << 2);
            short8 af0 = *(const short8*)&As[cur][(r0 << 6) + ((lc ^ (r0 & 7)) << 3)];
            short8 af1 = *(const short8*)&As[cur][(r1 << 6) + ((lc ^ (r1 & 7)) << 3)];
            short8 bf0 = *(const short8*)&Bs[cur][(c0 << 6) + ((lc ^ (c0 & 7)) << 3)];
            short8 bf1 = *(const short8*)&Bs[cur][(c1 << 6) + ((lc ^ (c1 & 7)) << 3)];
            acc[0][0] = __builtin_amdgcn_mfma_f32_16x16x32_bf16(af0, bf0, acc[0][0], 0, 0, 0);
            acc[0][1] = __builtin_amdgcn_mfma_f32_16x16x32_bf16(af0, bf1, acc[0][1], 0, 0, 0);
            acc[1][0] = __builtin_amdgcn_mfma_f32_16x16x32_bf16(af1, bf0, acc[1][0], 0, 0, 0);
            acc[1][1] = __builtin_amdgcn_mfma_f32_16x16x32_bf16(af1, bf1, acc[1][1], 0, 0, 0);
        }
        __syncthreads();
    }

    #pragma unroll
    for (int i = 0; i < 2; i++) {
        #pragma unroll
        for (int j = 0; j < 2; j++) {
            const int nl  = n0 + wc + (j << 4) + fr;
            const int mlb = m0 + wr + (i << 4) + (fq << 2);
            const float bsv = (bias && blockIdx.z == 0) ? bias[nl] : 0.f;
            #pragma unroll
            for (int r = 0; r < 4; r++) {
                const int ml = mlb + r;
                float v = acc[i][j][r] + bsv;
                if (ns > 1) unsafeAtomicAdd(&Cf[(long)ml * csm + nl], v);
                else        Cf[(long)ml * csm + nl] = v;
            }
        }
    }
}

// ---------------------------------------------------------------------------
// gemm_big: 128x128 tile, 4 waves each 64x64, BK=32, double-buffered,
// one barrier per K-step; LDS chunk swizzle c^((r>>1)&3) -> conflict-free.
// Logits GEMM only (f32 out).
// ---------------------------------------------------------------------------
__global__ __launch_bounds__(256) void gemm_big(
    const u16* __restrict__ A, int lda,
    const u16* __restrict__ B, int ldb,
    float* Cf, int ldc,
    const float* __restrict__ bias, int K)
{
    __shared__ u16 As[2][4096];   // 128 rows x 32 k
    __shared__ u16 Bs[2][4096];
    int mt, nt; swz_tile(mt, nt);
    const int m0 = mt << 7, n0 = nt << 7;
    const int t = threadIdx.x, lane = t & 63, wave = t >> 6;
    const int wr = (wave >> 1) << 6, wc = (wave & 1) << 6;
    const int fr = lane & 15, fq = lane >> 4;
    const int srow = t >> 2;
    const int sch  = (t & 3) ^ ((srow >> 1) & 3);
    const u16* Ag0 = A + (long)(m0 + srow) * lda + (sch << 3);
    const u16* Ag1 = A + (long)(m0 + 64 + srow) * lda + (sch << 3);
    const u16* Bg0 = B + (long)(n0 + srow) * ldb + (sch << 3);
    const u16* Bg1 = B + (long)(n0 + 64 + srow) * ldb + (sch << 3);

    f32x4 acc[4][4];
    #pragma unroll
    for (int i = 0; i < 4; i++)
        #pragma unroll
        for (int j = 0; j < 4; j++) acc[i][j] = (f32x4){0.f, 0.f, 0.f, 0.f};

    const int nk = K >> 5;
    gl_lds16(Ag0, &As[0][t << 3]);
    gl_lds16(Ag1, &As[0][(t + 256) << 3]);
    gl_lds16(Bg0, &Bs[0][t << 3]);
    gl_lds16(Bg1, &Bs[0][(t + 256) << 3]);
    __syncthreads();
    for (int ki = 0; ki < nk; ki++) {
        const int cur = ki & 1;
        if (ki + 1 < nk) {
            const int ko = (ki + 1) << 5;
            gl_lds16(Ag0 + ko, &As[cur ^ 1][t << 3]);
            gl_lds16(Ag1 + ko, &As[cur ^ 1][(t + 256) << 3]);
            gl_lds16(Bg0 + ko, &Bs[cur ^ 1][t << 3]);
            gl_lds16(Bg1 + ko, &Bs[cur ^ 1][(t + 256) << 3]);
        }
        short8 af[4], bf[4];
        #pragma unroll
        for (int i = 0; i < 4; i++) {
            const int r = wr + (i << 4) + fr;
            af[i] = *(const short8*)&As[cur][(r << 5) + ((fq ^ ((r >> 1) & 3)) << 3)];
        }
        #pragma unroll
        for (int j = 0; j < 4; j++) {
            const int c = wc + (j << 4) + fr;
            bf[j] = *(const short8*)&Bs[cur][(c << 5) + ((fq ^ ((c >> 1) & 3)) << 3)];
        }
        #pragma unroll
        for (int i = 0; i < 4; i++)
            #pragma unroll
            for (int j = 0; j < 4; j++)
                acc[i][j] = __builtin_amdgcn_mfma_f32_16x16x32_bf16(af[i], bf[j], acc[i][j], 0, 0, 0);
        __syncthreads();
    }

    #pragma unroll
    for (int i = 0; i < 4; i++) {
        #pragma unroll
        for (int j = 0; j < 4; j++) {
            const int nl  = n0 + wc + (j << 4) + fr;
            const int mlb = m0 + wr + (i << 4) + (fq << 2);
            const float bsv = bias ? bias[nl] : 0.f;
            #pragma unroll
            for (int r = 0; r < 4; r++)
                Cf[(long)(mlb + r) * ldc + nl] = acc[i][j][r] + bsv;
        }
    }
}

// ---------------------------------------------------------------------------
// Fused attention: block per (q-tile 64, head, batch), 4 waves x 16 q-rows.
// K/V tiles in LDS, double-buffered, one barrier per tile; sources
// pre-swizzled (c' = c ^ (row&7)) so swizzled ds_reads are conflict-free.
// ---------------------------------------------------------------------------
__global__ __launch_bounds__(256) void attn_fused(
    const u16* __restrict__ qkb, const u16* __restrict__ vt,
    const int* __restrict__ ids, u16* __restrict__ attc, int causal)
{
    __shared__ u16 Ks[2][4096];
    __shared__ u16 Vs[2][4096];
    __shared__ short Ps[4][16][72];
    const int t = threadIdx.x, lane = t & 63, w = t >> 6;
    const int fr = lane & 15, fq = lane >> 4;
    const int q0 = blockIdx.x << 6, h = blockIdx.y, b = blockIdx.z;

    const u16* qp = qkb + (long)(b * 512 + q0 + (w << 4) + fr) * 1024 + h * 64 + (fq << 3);
    short8 aq0 = *(const short8*)qp;
    short8 aq1 = *(const short8*)(qp + 32);

    const int sr = t >> 3, sc = (t & 7) ^ (sr & 7);
    const u16* kg0 = qkb + (long)(b * 512 + sr) * 1024 + 512 + h * 64 + (sc << 3);
    const u16* kg1 = kg0 + 32L * 1024;
    const u16* vg0 = vt + (long)b * S2W + (long)(h * 64 + sr) * 512 + (sc << 3);
    const u16* vg1 = vg0 + 32L * 512;

    unsigned pmask = 0;
    #pragma unroll
    for (int kt = 0; kt < 8; kt++)
        #pragma unroll
        for (int j = 0; j < 4; j++)
            if (ids[b * 512 + (kt << 6) + (j << 4) + fr] == PADID)
                pmask |= 1u << ((kt << 2) + j);

    float m[4], l[4]; f32x4 oc[4];
    #pragma unroll
    for (int r = 0; r < 4; r++) { m[r] = -INFINITY; l[r] = 0.f; oc[r] = (f32x4){0.f,0.f,0.f,0.f}; }

    const int lastkt = causal ? (q0 >> 6) : 7;
    auto stage = [&](int kt, int buf) {
        const long so = (long)(kt << 6);
        gl_lds16(kg0 + so * 1024, &Ks[buf][t << 3]);
        gl_lds16(kg1 + so * 1024, &Ks[buf][(t + 256) << 3]);
        gl_lds16(vg0 + so, &Vs[buf][t << 3]);
        gl_lds16(vg1 + so, &Vs[buf][(t + 256) << 3]);
    };
    stage(0, 0);
    __syncthreads();

    for (int kt = 0; kt <= lastkt; kt++) {
        const int cur = kt & 1;
        if (kt < lastkt) stage(kt + 1, cur ^ 1);

        f32x4 sc4[4];
        #pragma unroll
        for (int j = 0; j < 4; j++) sc4[j] = (f32x4){0.f,0.f,0.f,0.f};
        #pragma unroll
        for (int j = 0; j < 4; j++) {
            const int rr = (j << 4) + fr;
            short8 bk0 = *(const short8*)&Ks[cur][rr * 64 + ((fq ^ (rr & 7)) << 3)];
            short8 bk1 = *(const short8*)&Ks[cur][rr * 64 + (((fq | 4) ^ (rr & 7)) << 3)];
            sc4[j] = __builtin_amdgcn_mfma_f32_16x16x32_bf16(aq0, bk0, sc4[j], 0, 0, 0);
            sc4[j] = __builtin_amdgcn_mfma_f32_16x16x32_bf16(aq1, bk1, sc4[j], 0, 0, 0);
        }
        const int s0 = kt << 6;
        #pragma unroll
        for (int r = 0; r < 4; r++) {
            const int qa = q0 + (w << 4) + (fq << 2) + r;
            float mx = -INFINITY;
            #pragma unroll
            for (int j = 0; j < 4; j++) {
                bool msk = ((pmask >> ((kt << 2) + j)) & 1) ||
                           (causal && (s0 + (j << 4) + fr) > qa);
                float sv = msk ? -INFINITY : sc4[j][r] * 0.125f;
                sc4[j][r] = sv;
                mx = fmaxf(mx, sv);
            }
            mx = fmaxf(mx, __shfl_xor(mx, 1)); mx = fmaxf(mx, __shfl_xor(mx, 2));
            mx = fmaxf(mx, __shfl_xor(mx, 4)); mx = fmaxf(mx, __shfl_xor(mx, 8));
            float mnew  = fmaxf(m[r], mx);
            float scale = (mnew == -INFINITY) ? 1.f : __expf(m[r] - mnew);
            float ps = 0.f;
            #pragma unroll
            for (int j = 0; j < 4; j++) {
                float p = (sc4[j][r] == -INFINITY) ? 0.f : __expf(sc4[j][r] - mnew);
                sc4[j][r] = p; ps += p;
            }
            ps += __shfl_xor(ps, 1); ps += __shfl_xor(ps, 2);
            ps += __shfl_xor(ps, 4); ps += __shfl_xor(ps, 8);
            l[r] = l[r] * scale + ps;
            m[r] = mnew;
            #pragma unroll
            for (int j2 = 0; j2 < 4; j2++) oc[j2][r] *= scale;
        }
        #pragma unroll
        for (int r = 0; r < 4; r++)
            #pragma unroll
            for (int j = 0; j < 4; j++)
                Ps[w][(fq << 2) + r][(j << 4) + fr] = (short)f2bf(sc4[j][r]);
        #pragma unroll
        for (int kc = 0; kc < 2; kc++) {
            short8 pa = *(const short8*)&Ps[w][fr][(kc << 5) + (fq << 3)];
            #pragma unroll
            for (int j2 = 0; j2 < 4; j2++) {
                const int rd = (j2 << 4) + fr;
                const int cch = (((kc << 2) | fq) ^ (rd & 7));
                short8 bv = *(const short8*)&Vs[cur][rd * 64 + (cch << 3)];
                oc[j2] = __builtin_amdgcn_mfma_f32_16x16x32_bf16(pa, bv, oc[j2], 0, 0, 0);
            }
        }
        __syncthreads();
    }

    float inv[4];
    #pragma unroll
    for (int r = 0; r < 4; r++) inv[r] = (l[r] > 0.f) ? 1.f / l[r] : 0.f;
    #pragma unroll
    for (int j2 = 0; j2 < 4; j2++)
        #pragma unroll
        for (int r = 0; r < 4; r++)
            attc[(long)(b * 512 + q0 + (w << 4) + (fq << 2) + r) * 512 + h * 64 + (j2 << 4) + fr]
                = f2bf(oc[j2][r] * inv[r]);
}

// LayerNorm over D=512: 4 rows/block (wave per row). f32 in -> bf16 out.
__global__ __launch_bounds__(256) void ln_rows(
    const float* __restrict__ x, const float* __restrict__ g,
    const float* __restrict__ b, u16* __restrict__ out)
{
    int row  = blockIdx.x * 4 + (threadIdx.x >> 6);
    int lane = threadIdx.x & 63;
    const float* xr = x + (long)row * Dm;
    float v[8]; float s = 0.f;
    #pragma unroll
    for (int i = 0; i < 8; i++) { v[i] = xr[lane + (i << 6)]; s += v[i]; }
    #pragma unroll
    for (int o = 32; o > 0; o >>= 1) s += __shfl_xor(s, o);
    float mean = s * (1.f / 512.f);
    float q = 0.f;
    #pragma unroll
    for (int i = 0; i < 8; i++) { float d = v[i] - mean; q += d * d; }
    #pragma unroll
    for (int o = 32; o > 0; o >>= 1) q += __shfl_xor(q, o);
    float rinv = rsqrtf(q * (1.f / 512.f) + LNEPS);
    u16* orow = out + (long)row * Dm;
    #pragma unroll
    for (int i = 0; i < 8; i++) {
        int c = lane + (i << 6);
        orow[c] = f2bf((v[i] - mean) * rinv * g[c] + b[c]);
    }
}

// x[b,s,:] = embed[id]*sqrt(D) + PE(s,:)   (f32 in/out)
__global__ __launch_bounds__(256) void embed_pe(
    const int* __restrict__ ids, const float* __restrict__ emb,
    float* __restrict__ out)
{
    int idx = blockIdx.x * 256 + threadIdx.x;   // NTOK*512 = 2^20
    int d   = idx & 511;
    int tok = idx >> 9;
    int s   = tok & 511;
    int id  = ids[tok];
    float val = emb[(long)id * Dm + d] * 22.62741699796952f;     // sqrt(512)
    int i2 = d >> 1;
    float dv  = expf((float)(i2 << 1) * (-9.210340371976184f / 512.f));
    float ang = (float)s * dv;
    val += (d & 1) ? cosf(ang) : sinf(ang);
    out[idx] = val;
}

// ---------------------------------------------------------------------------
extern "C" void kernel_launch(void* const* d_in, const int* in_sizes, int n_in,
                              void* d_out, int out_size, void* d_ws, size_t ws_size,
                              hipStream_t stream)
{
    (void)in_sizes; (void)n_in; (void)out_size; (void)ws_size;
    const int*   src       = (const int*)d_in[0];
    const int*   tgt       = (const int*)d_in[1];
    const float* src_embed = (const float*)d_in[2];
    const float* tgt_embed = (const float*)d_in[3];
    const float* enc_b1  = (const float*)d_in[9];
    const float* enc_b2  = (const float*)d_in[11];
    const float* enc_ln1g = (const float*)d_in[12];
    const float* enc_ln1b = (const float*)d_in[13];
    const float* enc_ln2g = (const float*)d_in[14];
    const float* enc_ln2b = (const float*)d_in[15];
    const float* enc_lnfg = (const float*)d_in[16];
    const float* enc_lnfb = (const float*)d_in[17];
    const float* dec_b1  = (const float*)d_in[27];
    const float* dec_b2  = (const float*)d_in[29];
    const float* dec_ln1g = (const float*)d_in[30];
    const float* dec_ln1b = (const float*)d_in[31];
    const float* dec_ln2g = (const float*)d_in[32];
    const float* dec_ln2b = (const float*)d_in[33];
    const float* dec_ln3g = (const float*)d_in[34];
    const float* dec_ln3b = (const float*)d_in[35];
    const float* dec_lnfg = (const float*)d_in[36];
    const float* dec_lnfb = (const float*)d_in[37];
    const float* out_b  = (const float*)d_in[39];

    char* wp = (char*)d_ws;
    auto carve = [&](size_t nbytes) {
        void* p = (void*)wp; wp += (nbytes + 255) & ~(size_t)255; return p;
    };

    const long nW = (long)NLay * S2W;
    const long nF = (long)NLay * DFFm * Dm;
    const long nO = 32000L * Dm;

    u16* Wb[12];
    for (int i = 0; i < 12; i++) Wb[i] = (u16*)carve((size_t)nW * 2);
    u16* w1E  = (u16*)carve((size_t)nF * 2);
    u16* w2E  = (u16*)carve((size_t)nF * 2);
    u16* w1D  = (u16*)carve((size_t)nF * 2);
    u16* w2D  = (u16*)carve((size_t)nF * 2);
    u16* outW = (u16*)carve((size_t)nO * 2);

    float* x  = (float*)carve((size_t)NTOK * Dm * 4);
    float* y  = (float*)carve((size_t)NTOK * Dm * 4);
    u16* nrm  = (u16*)carve((size_t)NTOK * Dm * 2);
    u16* qkb  = (u16*)carve((size_t)NTOK * 1024 * 2);
    u16* vt   = (u16*)carve((size_t)Bb * Dm * 512 * 2);
    u16* attc = (u16*)carve((size_t)NTOK * Dm * 2);
    u16* h1   = (u16*)carve((size_t)NTOK * DFFm * 2);

    // d_in indices for the 12 attn weight tensors, matching Wb order:
    // eWq eWk eWv eWo | sWq sWk sWv sWo | cWq cWk cWv cWo
    const int wi[12] = {4, 5, 6, 7, 18, 19, 20, 21, 22, 23, 24, 25};
    CvtJobs jobs;
    for (int i = 0; i < 12; i++) {
        jobs.s[i] = (const float*)d_in[wi[i]]; jobs.d[i] = Wb[i]; jobs.n4[i] = nW >> 2;
    }
    jobs.s[12] = (const float*)d_in[8];  jobs.d[12] = w1E;  jobs.n4[12] = nF >> 2;
    jobs.s[13] = (const float*)d_in[10]; jobs.d[13] = w2E;  jobs.n4[13] = nF >> 2;
    jobs.s[14] = (const float*)d_in[26]; jobs.d[14] = w1D;  jobs.n4[14] = nF >> 2;
    jobs.s[15] = (const float*)d_in[28]; jobs.d[15] = w2D;  jobs.n4[15] = nF >> 2;
    jobs.s[16] = (const float*)d_in[38]; jobs.d[16] = outW; jobs.n4[16] = nO >> 2;
    cvt_many<<<dim3(512, 17), 256, 0, stream>>>(jobs);

    const int BIG = 1 << 28;
    u16 *eWq = Wb[0], *eWk = Wb[1], *eWv = Wb[2], *eWo = Wb[3];
    u16 *sWq = Wb[4], *sWk = Wb[5], *sWv = Wb[6], *sWo = Wb[7];
    u16 *cWq = Wb[8], *cWk = Wb[9], *cWv = Wb[10], *cWo = Wb[11];

    const size_t LNB = 64 * 512 * 2 + 2 * 2048 * 2;   // 73728 B -> 2 blocks/CU

    // ---------------- Encoder ----------------
    embed_pe<<<4096, 256, 0, stream>>>(src, src_embed, x);
    for (int l = 0; l < NLay; l++) {
        const size_t wo = (size_t)l * S2W;
        // QKV with fused LN(ln1): qkb[:,0:512]=Q, [:,512:1024]=K, vt=V^T
        gemm_lnbt<<<dim3(24, 32), 256, LNB, stream>>>(
            x, x, enc_ln1g + l * Dm, enc_ln1b + l * Dm, enc_ln1g + l * Dm, enc_ln1b + l * Dm,
            eWq + wo, eWk + wo, eWv + wo, qkb, 1024, nullptr, 0, 1024, vt);
        attn_fused<<<dim3(8, Hh, Bb), 256, 0, stream>>>(qkb, vt, src, attc, 0);
        // x += attc @ Wo^T (splitK2, atomic)
        gemm_bt<<<dim3(8, 32, 2), 256, 0, stream>>>(attc, 512, eWo + wo, 512,
            x, 512, nullptr, 256, 2);
        // h1 = relu(LN(x,ln2) @ w1^T + b1)
        gemm_lnbt<<<dim3(32, 32), 256, LNB, stream>>>(
            x, x, enc_ln2g + l * Dm, enc_ln2b + l * Dm, enc_ln2g + l * Dm, enc_ln2b + l * Dm,
            w1E + (size_t)l * DFFm * Dm, nullptr, nullptr, h1, DFFm,
            enc_b1 + l * DFFm, 1, BIG, nullptr);
        // x += h1 @ w2^T + b2 (splitK4, atomic)
        gemm_bt<<<dim3(8, 32, 4), 256, 0, stream>>>(h1, DFFm, w2E + (size_t)l * Dm * DFFm, DFFm,
            x, 512, enc_b2 + l * Dm, 512, 4);
    }
    // (final encoder LN is recomputed inside each decoder cross-QKV dispatch)

    // ---------------- Decoder ----------------
    embed_pe<<<4096, 256, 0, stream>>>(tgt, tgt_embed, y);
    for (int l = 0; l < NLay; l++) {
        const size_t wo = (size_t)l * S2W;
        // self-attention (causal + tgt pad), LN(ln1) fused
        gemm_lnbt<<<dim3(24, 32), 256, LNB, stream>>>(
            y, y, dec_ln1g + l * Dm, dec_ln1b + l * Dm, dec_ln1g + l * Dm, dec_ln1b + l * Dm,
            sWq + wo, sWk + wo, sWv + wo, qkb, 1024, nullptr, 0, 1024, vt);
        attn_fused<<<dim3(8, Hh, Bb), 256, 0, stream>>>(qkb, vt, tgt, attc, 1);
        gemm_bt<<<dim3(8, 32, 2), 256, 0, stream>>>(attc, 512, sWo + wo, 512,
            y, 512, nullptr, 256, 2);
        // cross-attention: Q from LN(y,ln2); K,V from LN(x_enc,lnfE)
        gemm_lnbt<<<dim3(24, 32), 256, LNB, stream>>>(
            y, x, dec_ln2g + l * Dm, dec_ln2b + l * Dm, enc_lnfg, enc_lnfb,
            cWq + wo, cWk + wo, cWv + wo, qkb, 1024, nullptr, 0, 1024, vt);
        attn_fused<<<dim3(8, Hh, Bb), 256, 0, stream>>>(qkb, vt, src, attc, 0);
        gemm_bt<<<dim3(8, 32, 2), 256, 0, stream>>>(attc, 512, cWo + wo, 512,
            y, 512, nullptr, 256, 2);
        // FFN with fused LN(ln3)
        gemm_lnbt<<<dim3(32, 32), 256, LNB, stream>>>(
            y, y, dec_ln3g + l * Dm, dec_ln3b + l * Dm, dec_ln3g + l * Dm, dec_ln3b + l * Dm,
            w1D + (size_t)l * DFFm * Dm, nullptr, nullptr, h1, DFFm,
            dec_b1 + l * DFFm, 1, BIG, nullptr);
        gemm_bt<<<dim3(8, 32, 4), 256, 0, stream>>>(h1, DFFm, w2D + (size_t)l * Dm * DFFm, DFFm,
            y, 512, dec_b2 + l * Dm, 512, 4);
    }
    ln_rows<<<512, 256, 0, stream>>>(y, dec_lnfg, dec_lnfb, nrm);

    // final projection to vocab: [2048][32000] f32 out
    gemm_big<<<dim3(250, 16), 256, 0, stream>>>(nrm, 512, outW, 512,
        (float*)d_out, 32000, out_b, 512);
}

// Round 10
// 1743.808 us; speedup vs baseline: 2.0742x; 1.7461x over previous
//
#include <hip/hip_runtime.h>
#include <hip/hip_bf16.h>
#include <math.h>

// ---------------- problem constants ----------------
#define Dm    512
#define Hh    8
#define NLay  6
#define DFFm  2048
#define Bb    4
#define NTOK  2048          // B * S
#define PADID 1
#define LNEPS 1e-5f
#define S2W   262144        // 512*512 elements

typedef __attribute__((ext_vector_type(8))) short short8;   // 8 x bf16
typedef __attribute__((ext_vector_type(4))) float f32x4;
typedef unsigned short u16;

__device__ __forceinline__ u16 f2bf(float f) {
    union { float f; unsigned int i; } x; x.f = f;
    unsigned int r = x.i + 0x7fffu + ((x.i >> 16) & 1u);   // RNE
    return (u16)(r >> 16);
}

// async global->LDS, 16B per lane (dest linear-in-lane: base+lane*16)
typedef const __attribute__((address_space(1))) void* as1cv;
typedef __attribute__((address_space(3))) void* as3v;
__device__ __forceinline__ void gl_lds16(const u16* g, u16* l) {
    __builtin_amdgcn_global_load_lds((as1cv)g, (as3v)l, 16, 0, 0);
}

// counted-vmcnt sync (T3/T4): wait N oldest loads, raw barrier, fence (rule #18)
#define SYNC_VM(N) do { \
    asm volatile("s_waitcnt vmcnt(" #N ")" ::: "memory"); \
    __builtin_amdgcn_s_barrier(); \
    __builtin_amdgcn_sched_barrier(0); \
} while (0)

// bijective XCD-chunk swizzle (m204), M fastest within an XCD's chunk.
__device__ __forceinline__ void swz_tile(int& mt, int& nt) {
    const int nwg  = gridDim.x * gridDim.y;
    const int orig = blockIdx.y * gridDim.x + blockIdx.x;
    const int q8 = nwg >> 3, r8 = nwg & 7;
    const int xcd = orig & 7, idx = orig >> 3;
    const int wgid = (xcd < r8 ? xcd * (q8 + 1) : r8 * (q8 + 1) + (xcd - r8) * q8) + idx;
    const int MT = gridDim.y;
    mt = wgid % MT;
    nt = wgid / MT;
}

// ---- one-launch f32->bf16 conversion of all 17 weight tensors ----
struct CvtJobs {
    const float* s[17];
    u16*         d[17];
    long         n4[17];
};
__global__ __launch_bounds__(256) void cvt_many(CvtJobs j) {
    const int job = blockIdx.y;
    const long n4 = j.n4[job];
    const float* in = j.s[job];
    u16* out = j.d[job];
    long i = (long)blockIdx.x * 256 + threadIdx.x;
    const long stride = (long)gridDim.x * 256;
    for (; i < n4; i += stride) {
        float4 v = ((const float4*)in)[i];
        ushort4 o;
        o.x = f2bf(v.x); o.y = f2bf(v.y); o.z = f2bf(v.z); o.w = f2bf(v.w);
        ((ushort4*)out)[i] = o;
    }
}

// ---------------------------------------------------------------------------
// gemm_bt: C[m,n] = sum_k A[m,k]*B[n,k] (+bias[n]) (+relu)
// 64x64 tile, BK=64, 3-buffer pipeline with counted vmcnt: loads for tile
// k+2 stay in flight across the barrier (only k+1's 4 loads are waited).
// Per-512-col part: p = n0>>9 selects (A0..A2, B0..B2); if B1==nullptr the
// B matrix is contiguous and n indexes B0 directly.
// Split-K: grid.z = ns slices of Kc; ns>1 -> unsafeAtomicAdd f32 into Cf.
// ns==1 epilogue: nl >= vth -> vt[b][nl-vth][s]; else C[ml*csm + nl + koff].
// ---------------------------------------------------------------------------
__global__ __launch_bounds__(256) void gemm_bt(
    const u16* __restrict__ A0, const u16* __restrict__ A1,
    const u16* __restrict__ A2, int lda,
    const u16* __restrict__ B0, const u16* __restrict__ B1,
    const u16* __restrict__ B2, int ldb,
    float* Cf, u16* Cb, int csm,
    const float* __restrict__ bias, int relu,
    int Kc, int ns, int vth, int koff, u16* vtp)
{
    __shared__ u16 As[3][4096];   // 64 rows x 64 k each
    __shared__ u16 Bs[3][4096];
    int mt, nt; swz_tile(mt, nt);
    const int m0 = mt << 6, n0 = nt << 6;
    const int t = threadIdx.x, lane = t & 63, wave = t >> 6;
    const int wr = (wave >> 1) << 5, wc = (wave & 1) << 5;
    const int fr = lane & 15, fq = lane >> 4;
    const int srow = t >> 3;
    const int sch  = (t & 7) ^ (srow & 7);

    const int p = n0 >> 9;
    const u16* Amat = (p == 0) ? A0 : (p == 1 ? A1 : A2);
    const u16* Bmat; int nb;
    if (B1) { Bmat = (p == 0) ? B0 : (p == 1 ? B1 : B2); nb = n0 & 511; }
    else    { Bmat = B0; nb = n0; }
    const long kb = (long)blockIdx.z * Kc;

    const u16* Ag0 = Amat + (long)(m0 + srow) * lda + kb + (sch << 3);
    const u16* Ag1 = Ag0 + 32L * lda;
    const u16* Bg0 = Bmat + (long)(nb + srow) * ldb + kb + (sch << 3);
    const u16* Bg1 = Bg0 + 32L * ldb;

    f32x4 acc[2][2];
    #pragma unroll
    for (int i = 0; i < 2; i++)
        #pragma unroll
        for (int j = 0; j < 2; j++) acc[i][j] = (f32x4){0.f, 0.f, 0.f, 0.f};

    const int nk = Kc >> 6;
    auto stage = [&](int ki, int buf) {
        const int ko = ki << 6;
        gl_lds16(Ag0 + ko, &As[buf][t << 3]);
        gl_lds16(Ag1 + ko, &As[buf][(t + 256) << 3]);
        gl_lds16(Bg0 + ko, &Bs[buf][t << 3]);
        gl_lds16(Bg1 + ko, &Bs[buf][(t + 256) << 3]);
    };
    stage(0, 0);
    if (nk > 1) { stage(1, 1); SYNC_VM(4); }
    else        { SYNC_VM(0); }

    int cur = 0;
    for (int ki = 0; ki < nk; ki++) {
        const bool st = (ki + 2 < nk);
        if (st) stage(ki + 2, cur == 0 ? 2 : cur - 1);   // buf (cur+2)%3
        const int r0 = wr + fr, r1 = wr + 16 + fr;
        const int c0 = wc + fr, c1 = wc + 16 + fr;
        #pragma unroll
        for (int h = 0; h < 2; h++) {
            const int lc = fq | (h << 2);
            short8 af0 = *(const short8*)&As[cur][(r0 << 6) + ((lc ^ (r0 & 7)) << 3)];
            short8 af1 = *(const short8*)&As[cur][(r1 << 6) + ((lc ^ (r1 & 7)) << 3)];
            short8 bf0 = *(const short8*)&Bs[cur][(c0 << 6) + ((lc ^ (c0 & 7)) << 3)];
            short8 bf1 = *(const short8*)&Bs[cur][(c1 << 6) + ((lc ^ (c1 & 7)) << 3)];
            acc[0][0] = __builtin_amdgcn_mfma_f32_16x16x32_bf16(af0, bf0, acc[0][0], 0, 0, 0);
            acc[0][1] = __builtin_amdgcn_mfma_f32_16x16x32_bf16(af0, bf1, acc[0][1], 0, 0, 0);
            acc[1][0] = __builtin_amdgcn_mfma_f32_16x16x32_bf16(af1, bf0, acc[1][0], 0, 0, 0);
            acc[1][1] = __builtin_amdgcn_mfma_f32_16x16x32_bf16(af1, bf1, acc[1][1], 0, 0, 0);
        }
        if (ki + 1 < nk) {
            if (st) SYNC_VM(4);
            else    SYNC_VM(0);
        }
        cur = (cur == 2) ? 0 : cur + 1;
    }

    #pragma unroll
    for (int i = 0; i < 2; i++) {
        #pragma unroll
        for (int j = 0; j < 2; j++) {
            const int nl  = n0 + wc + (j << 4) + fr;
            const int mlb = m0 + wr + (i << 4) + (fq << 2);
            const float bsv = bias ? bias[nl] : 0.f;
            #pragma unroll
            for (int r = 0; r < 4; r++) {
                const int ml = mlb + r;
                if (ns > 1) {
                    float v = acc[i][j][r] + (blockIdx.z == 0 ? bsv : 0.f);
                    unsafeAtomicAdd(&Cf[(long)ml * csm + nl + koff], v);
                } else {
                    float v = acc[i][j][r] + bsv;
                    if (nl >= vth) {
                        vtp[(long)(ml >> 9) * S2W + (long)(nl - vth) * 512 + (ml & 511)] = f2bf(v);
                    } else {
                        if (relu) v = fmaxf(v, 0.f);
                        long ci = (long)ml * csm + nl + koff;
                        if (Cf) Cf[ci] = v;
                        if (Cb) Cb[ci] = f2bf(v);
                    }
                }
            }
        }
    }
}

// ---------------------------------------------------------------------------
// gemm_big: 128x128 tile, BK=32, 3-buffer counted-vmcnt pipeline; LDS chunk
// swizzle c^((r>>1)&3). Logits GEMM only (f32 out).
// ---------------------------------------------------------------------------
__global__ __launch_bounds__(256) void gemm_big(
    const u16* __restrict__ A, int lda,
    const u16* __restrict__ B, int ldb,
    float* Cf, int ldc,
    const float* __restrict__ bias, int K)
{
    __shared__ u16 As[3][4096];   // 128 rows x 32 k each
    __shared__ u16 Bs[3][4096];
    int mt, nt; swz_tile(mt, nt);
    const int m0 = mt << 7, n0 = nt << 7;
    const int t = threadIdx.x, lane = t & 63, wave = t >> 6;
    const int wr = (wave >> 1) << 6, wc = (wave & 1) << 6;
    const int fr = lane & 15, fq = lane >> 4;
    const int srow = t >> 2;
    const int sch  = (t & 3) ^ ((srow >> 1) & 3);
    const u16* Ag0 = A + (long)(m0 + srow) * lda + (sch << 3);
    const u16* Ag1 = A + (long)(m0 + 64 + srow) * lda + (sch << 3);
    const u16* Bg0 = B + (long)(n0 + srow) * ldb + (sch << 3);
    const u16* Bg1 = B + (long)(n0 + 64 + srow) * ldb + (sch << 3);

    f32x4 acc[4][4];
    #pragma unroll
    for (int i = 0; i < 4; i++)
        #pragma unroll
        for (int j = 0; j < 4; j++) acc[i][j] = (f32x4){0.f, 0.f, 0.f, 0.f};

    const int nk = K >> 5;
    auto stage = [&](int ki, int buf) {
        const int ko = ki << 5;
        gl_lds16(Ag0 + ko, &As[buf][t << 3]);
        gl_lds16(Ag1 + ko, &As[buf][(t + 256) << 3]);
        gl_lds16(Bg0 + ko, &Bs[buf][t << 3]);
        gl_lds16(Bg1 + ko, &Bs[buf][(t + 256) << 3]);
    };
    stage(0, 0);
    if (nk > 1) { stage(1, 1); SYNC_VM(4); }
    else        { SYNC_VM(0); }

    int cur = 0;
    for (int ki = 0; ki < nk; ki++) {
        const bool st = (ki + 2 < nk);
        if (st) stage(ki + 2, cur == 0 ? 2 : cur - 1);
        short8 af[4], bf[4];
        #pragma unroll
        for (int i = 0; i < 4; i++) {
            const int r = wr + (i << 4) + fr;
            af[i] = *(const short8*)&As[cur][(r << 5) + ((fq ^ ((r >> 1) & 3)) << 3)];
        }
        #pragma unroll
        for (int j = 0; j < 4; j++) {
            const int c = wc + (j << 4) + fr;
            bf[j] = *(const short8*)&Bs[cur][(c << 5) + ((fq ^ ((c >> 1) & 3)) << 3)];
        }
        #pragma unroll
        for (int i = 0; i < 4; i++)
            #pragma unroll
            for (int j = 0; j < 4; j++)
                acc[i][j] = __builtin_amdgcn_mfma_f32_16x16x32_bf16(af[i], bf[j], acc[i][j], 0, 0, 0);
        if (ki + 1 < nk) {
            if (st) SYNC_VM(4);
            else    SYNC_VM(0);
        }
        cur = (cur == 2) ? 0 : cur + 1;
    }

    #pragma unroll
    for (int i = 0; i < 4; i++) {
        #pragma unroll
        for (int j = 0; j < 4; j++) {
            const int nl  = n0 + wc + (j << 4) + fr;
            const int mlb = m0 + wr + (i << 4) + (fq << 2);
            const float bsv = bias ? bias[nl] : 0.f;
            #pragma unroll
            for (int r = 0; r < 4; r++)
                Cf[(long)(mlb + r) * ldc + nl] = acc[i][j][r] + bsv;
        }
    }
}

// ---------------------------------------------------------------------------
// Fused attention: block per (q-tile 64, head, batch), 4 waves x 16 q-rows.
// K/V tiles in LDS, double-buffered, __syncthreads per tile (unchanged R7).
// ---------------------------------------------------------------------------
__global__ __launch_bounds__(256) void attn_fused(
    const u16* __restrict__ qkb, const u16* __restrict__ vt,
    const int* __restrict__ ids, u16* __restrict__ attc, int causal)
{
    __shared__ u16 Ks[2][4096];
    __shared__ u16 Vs[2][4096];
    __shared__ short Ps[4][16][72];
    const int t = threadIdx.x, lane = t & 63, w = t >> 6;
    const int fr = lane & 15, fq = lane >> 4;
    const int q0 = blockIdx.x << 6, h = blockIdx.y, b = blockIdx.z;

    const u16* qp = qkb + (long)(b * 512 + q0 + (w << 4) + fr) * 1024 + h * 64 + (fq << 3);
    short8 aq0 = *(const short8*)qp;
    short8 aq1 = *(const short8*)(qp + 32);

    const int sr = t >> 3, sc = (t & 7) ^ (sr & 7);
    const u16* kg0 = qkb + (long)(b * 512 + sr) * 1024 + 512 + h * 64 + (sc << 3);
    const u16* kg1 = kg0 + 32L * 1024;
    const u16* vg0 = vt + (long)b * S2W + (long)(h * 64 + sr) * 512 + (sc << 3);
    const u16* vg1 = vg0 + 32L * 512;

    unsigned pmask = 0;
    #pragma unroll
    for (int kt = 0; kt < 8; kt++)
        #pragma unroll
        for (int j = 0; j < 4; j++)
            if (ids[b * 512 + (kt << 6) + (j << 4) + fr] == PADID)
                pmask |= 1u << ((kt << 2) + j);

    float m[4], l[4]; f32x4 oc[4];
    #pragma unroll
    for (int r = 0; r < 4; r++) { m[r] = -INFINITY; l[r] = 0.f; oc[r] = (f32x4){0.f,0.f,0.f,0.f}; }

    const int lastkt = causal ? (q0 >> 6) : 7;
    auto stage = [&](int kt, int buf) {
        const long so = (long)(kt << 6);
        gl_lds16(kg0 + so * 1024, &Ks[buf][t << 3]);
        gl_lds16(kg1 + so * 1024, &Ks[buf][(t + 256) << 3]);
        gl_lds16(vg0 + so, &Vs[buf][t << 3]);
        gl_lds16(vg1 + so, &Vs[buf][(t + 256) << 3]);
    };
    stage(0, 0);
    __syncthreads();

    for (int kt = 0; kt <= lastkt; kt++) {
        const int cur = kt & 1;
        if (kt < lastkt) stage(kt + 1, cur ^ 1);

        f32x4 sc4[4];
        #pragma unroll
        for (int j = 0; j < 4; j++) sc4[j] = (f32x4){0.f,0.f,0.f,0.f};
        #pragma unroll
        for (int j = 0; j < 4; j++) {
            const int rr = (j << 4) + fr;
            short8 bk0 = *(const short8*)&Ks[cur][rr * 64 + ((fq ^ (rr & 7)) << 3)];
            short8 bk1 = *(const short8*)&Ks[cur][rr * 64 + (((fq | 4) ^ (rr & 7)) << 3)];
            sc4[j] = __builtin_amdgcn_mfma_f32_16x16x32_bf16(aq0, bk0, sc4[j], 0, 0, 0);
            sc4[j] = __builtin_amdgcn_mfma_f32_16x16x32_bf16(aq1, bk1, sc4[j], 0, 0, 0);
        }
        const int s0 = kt << 6;
        #pragma unroll
        for (int r = 0; r < 4; r++) {
            const int qa = q0 + (w << 4) + (fq << 2) + r;
            float mx = -INFINITY;
            #pragma unroll
            for (int j = 0; j < 4; j++) {
                bool msk = ((pmask >> ((kt << 2) + j)) & 1) ||
                           (causal && (s0 + (j << 4) + fr) > qa);
                float sv = msk ? -INFINITY : sc4[j][r] * 0.125f;
                sc4[j][r] = sv;
                mx = fmaxf(mx, sv);
            }
            mx = fmaxf(mx, __shfl_xor(mx, 1)); mx = fmaxf(mx, __shfl_xor(mx, 2));
            mx = fmaxf(mx, __shfl_xor(mx, 4)); mx = fmaxf(mx, __shfl_xor(mx, 8));
            float mnew  = fmaxf(m[r], mx);
            float scale = (mnew == -INFINITY) ? 1.f : __expf(m[r] - mnew);
            float ps = 0.f;
            #pragma unroll
            for (int j = 0; j < 4; j++) {
                float p2 = (sc4[j][r] == -INFINITY) ? 0.f : __expf(sc4[j][r] - mnew);
                sc4[j][r] = p2; ps += p2;
            }
            ps += __shfl_xor(ps, 1); ps += __shfl_xor(ps, 2);
            ps += __shfl_xor(ps, 4); ps += __shfl_xor(ps, 8);
            l[r] = l[r] * scale + ps;
            m[r] = mnew;
            #pragma unroll
            for (int j2 = 0; j2 < 4; j2++) oc[j2][r] *= scale;
        }
        #pragma unroll
        for (int r = 0; r < 4; r++)
            #pragma unroll
            for (int j = 0; j < 4; j++)
                Ps[w][(fq << 2) + r][(j << 4) + fr] = (short)f2bf(sc4[j][r]);
        #pragma unroll
        for (int kc = 0; kc < 2; kc++) {
            short8 pa = *(const short8*)&Ps[w][fr][(kc << 5) + (fq << 3)];
            #pragma unroll
            for (int j2 = 0; j2 < 4; j2++) {
                const int rd = (j2 << 4) + fr;
                const int cch = (((kc << 2) | fq) ^ (rd & 7));
                short8 bv = *(const short8*)&Vs[cur][rd * 64 + (cch << 3)];
                oc[j2] = __builtin_amdgcn_mfma_f32_16x16x32_bf16(pa, bv, oc[j2], 0, 0, 0);
            }
        }
        __syncthreads();
    }

    float inv[4];
    #pragma unroll
    for (int r = 0; r < 4; r++) inv[r] = (l[r] > 0.f) ? 1.f / l[r] : 0.f;
    #pragma unroll
    for (int j2 = 0; j2 < 4; j2++)
        #pragma unroll
        for (int r = 0; r < 4; r++)
            attc[(long)(b * 512 + q0 + (w << 4) + (fq << 2) + r) * 512 + h * 64 + (j2 << 4) + fr]
                = f2bf(oc[j2][r] * inv[r]);
}

// LayerNorm over D=512: 4 rows/block (wave per row). f32 in -> bf16 out.
__global__ __launch_bounds__(256) void ln_rows(
    const float* __restrict__ x, const float* __restrict__ g,
    const float* __restrict__ b, u16* __restrict__ out)
{
    int row  = blockIdx.x * 4 + (threadIdx.x >> 6);
    int lane = threadIdx.x & 63;
    const float* xr = x + (long)row * Dm;
    float v[8]; float s = 0.f;
    #pragma unroll
    for (int i = 0; i < 8; i++) { v[i] = xr[lane + (i << 6)]; s += v[i]; }
    #pragma unroll
    for (int o = 32; o > 0; o >>= 1) s += __shfl_xor(s, o);
    float mean = s * (1.f / 512.f);
    float q = 0.f;
    #pragma unroll
    for (int i = 0; i < 8; i++) { float d = v[i] - mean; q += d * d; }
    #pragma unroll
    for (int o = 32; o > 0; o >>= 1) q += __shfl_xor(q, o);
    float rinv = rsqrtf(q * (1.f / 512.f) + LNEPS);
    u16* orow = out + (long)row * Dm;
    #pragma unroll
    for (int i = 0; i < 8; i++) {
        int c = lane + (i << 6);
        orow[c] = f2bf((v[i] - mean) * rinv * g[c] + b[c]);
    }
}

// x[b,s,:] = embed[id]*sqrt(D) + PE(s,:)   (f32 in/out)
__global__ __launch_bounds__(256) void embed_pe(
    const int* __restrict__ ids, const float* __restrict__ emb,
    float* __restrict__ out)
{
    int idx = blockIdx.x * 256 + threadIdx.x;   // NTOK*512 = 2^20
    int d   = idx & 511;
    int tok = idx >> 9;
    int s   = tok & 511;
    int id  = ids[tok];
    float val = emb[(long)id * Dm + d] * 22.62741699796952f;     // sqrt(512)
    int i2 = d >> 1;
    float dv  = expf((float)(i2 << 1) * (-9.210340371976184f / 512.f));
    float ang = (float)s * dv;
    val += (d & 1) ? cosf(ang) : sinf(ang);
    out[idx] = val;
}

// ---------------------------------------------------------------------------
extern "C" void kernel_launch(void* const* d_in, const int* in_sizes, int n_in,
                              void* d_out, int out_size, void* d_ws, size_t ws_size,
                              hipStream_t stream)
{
    (void)in_sizes; (void)n_in; (void)out_size; (void)ws_size;
    const int*   src       = (const int*)d_in[0];
    const int*   tgt       = (const int*)d_in[1];
    const float* src_embed = (const float*)d_in[2];
    const float* tgt_embed = (const float*)d_in[3];
    const float* enc_b1  = (const float*)d_in[9];
    const float* enc_b2  = (const float*)d_in[11];
    const float* enc_ln1g = (const float*)d_in[12];
    const float* enc_ln1b = (const float*)d_in[13];
    const float* enc_ln2g = (const float*)d_in[14];
    const float* enc_ln2b = (const float*)d_in[15];
    const float* enc_lnfg = (const float*)d_in[16];
    const float* enc_lnfb = (const float*)d_in[17];
    const float* dec_b1  = (const float*)d_in[27];
    const float* dec_b2  = (const float*)d_in[29];
    const float* dec_ln1g = (const float*)d_in[30];
    const float* dec_ln1b = (const float*)d_in[31];
    const float* dec_ln2g = (const float*)d_in[32];
    const float* dec_ln2b = (const float*)d_in[33];
    const float* dec_ln3g = (const float*)d_in[34];
    const float* dec_ln3b = (const float*)d_in[35];
    const float* dec_lnfg = (const float*)d_in[36];
    const float* dec_lnfb = (const float*)d_in[37];
    const float* out_b  = (const float*)d_in[39];

    char* wp = (char*)d_ws;
    auto carve = [&](size_t nbytes) {
        void* p = (void*)wp; wp += (nbytes + 255) & ~(size_t)255; return p;
    };

    const long nW = (long)NLay * S2W;
    const long nF = (long)NLay * DFFm * Dm;
    const long nO = 32000L * Dm;

    u16* Wb[12];
    for (int i = 0; i < 12; i++) Wb[i] = (u16*)carve((size_t)nW * 2);
    u16* w1E  = (u16*)carve((size_t)nF * 2);
    u16* w2E  = (u16*)carve((size_t)nF * 2);
    u16* w1D  = (u16*)carve((size_t)nF * 2);
    u16* w2D  = (u16*)carve((size_t)nF * 2);
    u16* outW = (u16*)carve((size_t)nO * 2);

    float* x  = (float*)carve((size_t)NTOK * Dm * 4);
    float* y  = (float*)carve((size_t)NTOK * Dm * 4);
    u16* nrm  = (u16*)carve((size_t)NTOK * Dm * 2);
    u16* qkb  = (u16*)carve((size_t)NTOK * 1024 * 2);
    u16* vt   = (u16*)carve((size_t)Bb * Dm * 512 * 2);
    u16* attc = (u16*)carve((size_t)NTOK * Dm * 2);
    u16* h1   = (u16*)carve((size_t)NTOK * DFFm * 2);
    u16* memn = (u16*)carve((size_t)NTOK * Dm * 2);

    // d_in indices for the 12 attn weight tensors, matching Wb order:
    // eWq eWk eWv eWo | sWq sWk sWv sWo | cWq cWk cWv cWo
    const int wi[12] = {4, 5, 6, 7, 18, 19, 20, 21, 22, 23, 24, 25};
    CvtJobs jobs;
    for (int i = 0; i < 12; i++) {
        jobs.s[i] = (const float*)d_in[wi[i]]; jobs.d[i] = Wb[i]; jobs.n4[i] = nW >> 2;
    }
    jobs.s[12] = (const float*)d_in[8];  jobs.d[12] = w1E;  jobs.n4[12] = nF >> 2;
    jobs.s[13] = (const float*)d_in[10]; jobs.d[13] = w2E;  jobs.n4[13] = nF >> 2;
    jobs.s[14] = (const float*)d_in[26]; jobs.d[14] = w1D;  jobs.n4[14] = nF >> 2;
    jobs.s[15] = (const float*)d_in[28]; jobs.d[15] = w2D;  jobs.n4[15] = nF >> 2;
    jobs.s[16] = (const float*)d_in[38]; jobs.d[16] = outW; jobs.n4[16] = nO >> 2;
    cvt_many<<<dim3(512, 17), 256, 0, stream>>>(jobs);

    const int BIG = 1 << 28;
    u16 *eWq = Wb[0], *eWk = Wb[1], *eWv = Wb[2], *eWo = Wb[3];
    u16 *sWq = Wb[4], *sWk = Wb[5], *sWv = Wb[6], *sWo = Wb[7];
    u16 *cWq = Wb[8], *cWk = Wb[9], *cWv = Wb[10], *cWo = Wb[11];

    // ---------------- Encoder ----------------
    embed_pe<<<4096, 256, 0, stream>>>(src, src_embed, x);
    for (int l = 0; l < NLay; l++) {
        const size_t wo = (size_t)l * S2W;
        ln_rows<<<512, 256, 0, stream>>>(x, enc_ln1g + l * Dm, enc_ln1b + l * Dm, nrm);
        gemm_bt<<<dim3(24, 32, 1), 256, 0, stream>>>(nrm, nrm, nrm, 512,
            eWq + wo, eWk + wo, eWv + wo, 512,
            nullptr, qkb, 1024, nullptr, 0, 512, 1, 1024, 0, vt);
        attn_fused<<<dim3(8, Hh, Bb), 256, 0, stream>>>(qkb, vt, src, attc, 0);
        gemm_bt<<<dim3(8, 32, 2), 256, 0, stream>>>(attc, attc, attc, 512,
            eWo + wo, nullptr, nullptr, 512,
            x, nullptr, 512, nullptr, 0, 256, 2, BIG, 0, nullptr);
        ln_rows<<<512, 256, 0, stream>>>(x, enc_ln2g + l * Dm, enc_ln2b + l * Dm, nrm);
        gemm_bt<<<dim3(32, 32, 1), 256, 0, stream>>>(nrm, nrm, nrm, 512,
            w1E + (size_t)l * DFFm * Dm, nullptr, nullptr, 512,
            nullptr, h1, DFFm, enc_b1 + l * DFFm, 1, 512, 1, BIG, 0, nullptr);
        gemm_bt<<<dim3(8, 32, 4), 256, 0, stream>>>(h1, h1, h1, DFFm,
            w2E + (size_t)l * Dm * DFFm, nullptr, nullptr, DFFm,
            x, nullptr, 512, enc_b2 + l * Dm, 0, 512, 4, BIG, 0, nullptr);
    }
    ln_rows<<<512, 256, 0, stream>>>(x, enc_lnfg, enc_lnfb, memn);

    // ---------------- Decoder ----------------
    embed_pe<<<4096, 256, 0, stream>>>(tgt, tgt_embed, y);
    for (int l = 0; l < NLay; l++) {
        const size_t wo = (size_t)l * S2W;
        // self-attention (causal + tgt pad)
        ln_rows<<<512, 256, 0, stream>>>(y, dec_ln1g + l * Dm, dec_ln1b + l * Dm, nrm);
        gemm_bt<<<dim3(24, 32, 1), 256, 0, stream>>>(nrm, nrm, nrm, 512,
            sWq + wo, sWk + wo, sWv + wo, 512,
            nullptr, qkb, 1024, nullptr, 0, 512, 1, 1024, 0, vt);
        attn_fused<<<dim3(8, Hh, Bb), 256, 0, stream>>>(qkb, vt, tgt, attc, 1);
        gemm_bt<<<dim3(8, 32, 2), 256, 0, stream>>>(attc, attc, attc, 512,
            sWo + wo, nullptr, nullptr, 512,
            y, nullptr, 512, nullptr, 0, 256, 2, BIG, 0, nullptr);
        // cross-attention: merged Q(from y-norm) + K/V (from encoder memory)
        ln_rows<<<512, 256, 0, stream>>>(y, dec_ln2g + l * Dm, dec_ln2b + l * Dm, nrm);
        gemm_bt<<<dim3(24, 32, 1), 256, 0, stream>>>(nrm, memn, memn, 512,
            cWq + wo, cWk + wo, cWv + wo, 512,
            nullptr, qkb, 1024, nullptr, 0, 512, 1, 1024, 0, vt);
        attn_fused<<<dim3(8, Hh, Bb), 256, 0, stream>>>(qkb, vt, src, attc, 0);
        gemm_bt<<<dim3(8, 32, 2), 256, 0, stream>>>(attc, attc, attc, 512,
            cWo + wo, nullptr, nullptr, 512,
            y, nullptr, 512, nullptr, 0, 256, 2, BIG, 0, nullptr);
        // FFN
        ln_rows<<<512, 256, 0, stream>>>(y, dec_ln3g + l * Dm, dec_ln3b + l * Dm, nrm);
        gemm_bt<<<dim3(32, 32, 1), 256, 0, stream>>>(nrm, nrm, nrm, 512,
            w1D + (size_t)l * DFFm * Dm, nullptr, nullptr, 512,
            nullptr, h1, DFFm, dec_b1 + l * DFFm, 1, 512, 1, BIG, 0, nullptr);
        gemm_bt<<<dim3(8, 32, 4), 256, 0, stream>>>(h1, h1, h1, DFFm,
            w2D + (size_t)l * Dm * DFFm, nullptr, nullptr, DFFm,
            y, nullptr, 512, dec_b2 + l * Dm, 0, 512, 4, BIG, 0, nullptr);
    }
    ln_rows<<<512, 256, 0, stream>>>(y, dec_lnfg, dec_lnfb, nrm);

    // final projection to vocab: [2048][32000] f32 out
    gemm_big<<<dim3(250, 16), 256, 0, stream>>>(nrm, 512, outW, 512,
        (float*)d_out, 32000, out_b, 512);
}